// Round 8
// baseline (310.558 us; speedup 1.0000x reference)
//
#include <hip/hip_runtime.h>
#include <hip/hip_fp16.h>
#include <cstdint>
#include <cstddef>

// Problem constants (match reference setup_inputs)
#define NN   50000      // nodes  (< 65536: src/dst fit 16 bits)
#define NE   1200000    // edges
#define NR   45         // relations
#define INC  64
#define HIDC 32
#define OUTC 16
// Two-level edge bucketing: bucket = (src>>12)*NR + rel (sg-major).
// 13 src-groups x 45 relations = 585 buckets, each padded to a multiple of 64
// so every wave's 64 edges share one relation AND one 4096-src window
// (512 KB of xh / 256 KB of hh) -> gather working set fits per-XCD L2,
// cutting the 8x XCD re-fetch of xh/hh seen in msg1's FETCH counter.
#define NSG  13
#define NBKT (NSG * NR)                 // 585
#define MAXE (NE + NBKT * 64)           // 1237440, multiple of 64
#define NCHUNK (MAXE / 64)              // 19335
// relation counting-sort blocking
#define EPB 4096
#define NB  ((NE + EPB - 1) / EPB)      // 293 blocks
// relcnt: 4 dst-quarters per relation; 6250 LDS words x two u16 = 12500 dsts
#define QDW 6250
#define QDD 12500                       // 4*12500 = 50000 = NN exactly
// dp_k lookback tiles (256 dsts each)
#define NTILE ((NN + 255) / 256)        // 196

// Message rows are stored CHANNEL-INTERLEAVED (no LDS transpose needed):
//   layer-1 row word c (c=0..15) = half2{ ch c, ch c+16 }
//   layer-2 row word c (c=0..7)  = half2{ ch c, ch c+8  }
// hh is stored with the layer-1 interleave: stored element s <-> channel
// (s>>1) + (s&1)*16. W2f bakes the inverse permutation into its k index.
// Gathers read msg rows 16 B/lane and keep root weights in REGISTERS.
// finalize is FUSED into msg1 AND msg2 (both re-derive the per-edge record
// from rsorted/rank16/packed/rowptr/chunkrel) -> NO pedges buffer at all
// (-9.6 MB write in msg1, -9.6 MB read in msg2; packed/rowptr are L3-hot
// for msg2).
// msg stores go through an IN-WAVE shfl transpose (whole 64-B rows/instr).
// NOTE (round 2): nontemporal loads/stores REGRESSED badly. Default policy.
// NOTE (round 7): store coalescing + src-locality both individually null ->
// msg1 treated as BW-bound at ~4 TB/s for its mix; this round cuts BYTES.

typedef _Float16 f16x8 __attribute__((ext_vector_type(8)));
typedef float    f32x4 __attribute__((ext_vector_type(4)));

union F16Bits { unsigned short u; _Float16 f; };
union ABFrag   { uint4 u; f16x8 f; };

// ---------------------------------------------------------------------------
// Fused prep + bucket histogram + buffer init. All blocks do striped prep
// work (MFMA B-fragments in exact lane order + x f32->f16 cast + rsorted pad
// init + dp-flag zeroing + permuted root/bias tables); the first NB blocks
// also build the per-block 585-bin bucket histogram. ghist: [bucket][NB].
//   B[k][n] fragment for 16x16x32: lane holds k=(lane>>4)*8+j, n=lane&15.
__global__ __launch_bounds__(256) void preph_k(const float* __restrict__ W1,
                                               const float* __restrict__ W2,
                                               const float* __restrict__ x,
                                               const int* __restrict__ ei,
                                               const int* __restrict__ et,
                                               const float* __restrict__ root1,
                                               const float* __restrict__ root2,
                                               const float* __restrict__ b1,
                                               __half* __restrict__ W1f,
                                               __half* __restrict__ W2f,
                                               __half* __restrict__ xh,
                                               float2* __restrict__ rootp1,
                                               float2* __restrict__ rootp2,
                                               float2* __restrict__ b1p,
                                               unsigned* __restrict__ ghist,
                                               unsigned* __restrict__ rsorted,
                                               unsigned* __restrict__ flagbuf) {
    __shared__ unsigned lh[NBKT];     // 2.3 KB
    int t = threadIdx.x, b = blockIdx.x;
    for (int i = t; i < NBKT; i += 256) lh[i] = 0;
    __syncthreads();
    if (b < NB) {
        #pragma unroll
        for (int it = 0; it < EPB / 256; ++it) {
            int e = b * EPB + it * 256 + t;
            if (e < NE) {
                int r = et[e], src = ei[e], dst = ei[NE + e];
                if ((unsigned)r < NR && (unsigned)src < NN && (unsigned)dst < NN)
                    atomicAdd(&lh[(src >> 12) * NR + r], 1u);
            }
        }
    }
    __syncthreads();
    if (b < NB)
        for (int i = t; i < NBKT; i += 256) ghist[(size_t)i * NB + b] = lh[i];
    int g = b * 256 + t;
    int gthreads = gridDim.x * 256;
    // pad-sentinel init (replaces hipMemsetAsync node)
    for (int i = g; i < MAXE; i += gthreads) rsorted[i] = 0xFFFFFFFFu;
    if (b == 0) flagbuf[t] = 0;     // words 32..227: dp lookback flags
    if (g < NR * 2048) {
        int r = g >> 11, rem = g & 2047;
        int kb = rem >> 10, nb = (rem >> 9) & 1;
        int lane = (rem >> 3) & 63, j = rem & 7;
        int k = kb * 32 + (lane >> 4) * 8 + j;
        int n = nb * 16 + (lane & 15);
        W1f[g] = __float2half(W1[(r * INC + k) * HIDC + n]);
    }
    if (g < NR * 512) {
        int r = g >> 9, rem = g & 511;
        int lane = (rem >> 3) & 63, j = rem & 7;
        int k = (lane >> 4) * 8 + j;          // stored k index s
        int kc = (k >> 1) + ((k & 1) << 4);   // channel = perm(s) to match hh
        int n = lane & 15;
        W2f[g] = __float2half(W2[(r * HIDC + kc) * OUTC + n]);
    }
    if (g < NN * INC / 2) {
        float2 f = ((const float2*)x)[g];
        union { __half2 h; unsigned u; } cv;
        cv.h = __floats2half2_rn(f.x, f.y);
        ((unsigned*)xh)[g] = cv.u;
    }
    // permuted gather tables: rootp1[in*16+w] = {root1[in][w], root1[in][w+16]}
    if (g < 1024) {
        int in = g >> 4, w = g & 15;
        rootp1[g] = make_float2(root1[in * HIDC + w], root1[in * HIDC + w + 16]);
    }
    if (g < 256) {
        int in = g >> 3, w = g & 7;
        rootp2[g] = make_float2(root2[in * OUTC + w], root2[in * OUTC + w + 8]);
    }
    if (g < 16) b1p[g] = make_float2(b1[g], b1[g + 16]);
}

// ---------------------------------------------------------------------------
// scanA: one wave per bucket. Exclusive prefix over the bucket's NB per-block
// counts -> bbase row; total -> btot. Thread j owns elements j*5..j*5+4.
__global__ __launch_bounds__(64) void scanA_k(const unsigned* __restrict__ ghist,
                                              unsigned* __restrict__ bbase,
                                              unsigned* __restrict__ btot) {
    int b = blockIdx.x, j = threadIdx.x;
    const unsigned* __restrict__ row = ghist + (size_t)b * NB;
    unsigned* __restrict__ orow = bbase + (size_t)b * NB;
    unsigned v[5], s = 0;
    #pragma unroll
    for (int k = 0; k < 5; ++k) {
        int idx = j * 5 + k;
        v[k] = (idx < NB) ? row[idx] : 0u;
        s += v[k];
    }
    unsigned inc = s;
    #pragma unroll
    for (int off = 1; off < 64; off <<= 1) {
        unsigned n = __shfl_up(inc, off);
        if (j >= off) inc += n;
    }
    unsigned run = inc - s;
    #pragma unroll
    for (int k = 0; k < 5; ++k) {
        int idx = j * 5 + k;
        if (idx < NB) orow[idx] = run;
        run += v[k];
    }
    if (j == 63) btot[b] = inc;
}

// scanB: single block. Padded (to 64) exclusive scan of bucket totals ->
// gbase[NBKT+1]; fills chunkrel (relation of each 64-edge chunk).
__global__ __launch_bounds__(1024) void scanB_k(const unsigned* __restrict__ btot,
                                                unsigned* __restrict__ gbase,
                                                int* __restrict__ chunkrel) {
    __shared__ unsigned tot[NBKT];
    __shared__ unsigned gb[NBKT + 1];
    int t = threadIdx.x;
    for (int i = t; i < NBKT; i += 1024) tot[i] = btot[i];
    __syncthreads();
    if (t == 0) {
        unsigned acc = 0;
        for (int i = 0; i < NBKT; ++i) {
            gb[i] = acc;
            acc += (tot[i] + 63u) & ~63u;
        }
        gb[NBKT] = acc;
    }
    __syncthreads();
    for (int i = t; i <= NBKT; i += 1024) gbase[i] = gb[i];
    for (int c = t; c < NCHUNK; c += 1024) {
        unsigned pos = (unsigned)c << 6;
        int lo = 0, hi = NBKT - 1;
        while (lo < hi) {
            int mid = (lo + hi + 1) >> 1;
            if (gb[mid] <= pos) lo = mid; else hi = mid - 1;
        }
        chunkrel[c] = lo % NR;      // bucket = sg*NR + rel
    }
}

// ---------------------------------------------------------------------------
// Scatter into (src-group, relation) buckets. Block base comes directly from
// the precomputed tables: lbase[bkt] = gbase[bkt] + bbase[bkt][bx].
// Pads keep the 0xFFFFFFFF sentinel.
__global__ __launch_bounds__(1024) void scat_k(const int* __restrict__ ei,
                                               const int* __restrict__ et,
                                               const unsigned* __restrict__ bbase,
                                               const unsigned* __restrict__ gbase,
                                               unsigned* __restrict__ rsorted) {
    __shared__ unsigned lbase[NBKT], lcur[NBKT];
    int t = threadIdx.x, bx = blockIdx.x;
    for (int i = t; i < NBKT; i += 1024) {
        lbase[i] = gbase[i] + bbase[(size_t)i * NB + bx];
        lcur[i] = 0;
    }
    __syncthreads();
    #pragma unroll
    for (int it = 0; it < EPB / 1024; ++it) {
        int e = bx * EPB + it * 1024 + t;
        if (e < NE) {
            int r = et[e], src = ei[e], dst = ei[NE + e];
            if ((unsigned)r < NR && (unsigned)src < NN && (unsigned)dst < NN) {
                int bkt = (src >> 12) * NR + r;
                unsigned local = atomicAdd(&lcur[bkt], 1u);
                rsorted[lbase[bkt] + local] = (unsigned)src | ((unsigned)dst << 16);
            }
        }
    }
}

// Per-relation dst counts + per-edge rank in ONE pass (the atomic's old value
// is the rank; the final LDS word is the count). Four dst-quarters per
// relation; each relation spans NSG bucket segments [gbase[sg*NR+r], next).
// Pad slots (sentinel dst) are skipped by the range check.
__global__ __launch_bounds__(1024) void relcnt_k(const unsigned* __restrict__ rsorted,
                                                 const unsigned* __restrict__ gbase,
                                                 unsigned short* __restrict__ cnt16,
                                                 unsigned short* __restrict__ rank16) {
    __shared__ unsigned lds[QDW];     // 25000 B
    int r = blockIdx.x >> 2, q = blockIdx.x & 3, t = threadIdx.x;
    unsigned dlo = q * QDD, dhi = dlo + QDD;   // 4*12500 = NN exactly
    for (int w = t; w < QDW; w += 1024) lds[w] = 0;
    __syncthreads();
    for (int sg = 0; sg < NSG; ++sg) {
        unsigned base = gbase[sg * NR + r], end = gbase[sg * NR + r + 1];
        for (unsigned s = base + t; s < end; s += 1024) {
            unsigned d = rsorted[s] >> 16;
            if (d >= dlo && d < dhi) {
                unsigned off = d - dlo;
                unsigned old = atomicAdd(&lds[off >> 1], (off & 1) ? 0x10000u : 1u);
                rank16[s] = (unsigned short)((off & 1) ? (old >> 16) : (old & 0xFFFFu));
            }
        }
    }
    __syncthreads();
    unsigned* __restrict__ cp = (unsigned*)(cnt16 + (size_t)r * NN + dlo);
    for (int w = t; w < QDW; w += 1024) cp[w] = lds[w];
}

// ---------------------------------------------------------------------------
// Fused drel + dprefix via decoupled lookback. Tile = 256 dsts. Per dst:
// relation-prefix offsets + f16 inverse counts packed into one word per
// (r,dst); block-scan of degrees; lookback chain carries block sums INSIDE
// the atomic flag word {state:2 | sum:30} -> no non-atomic cross-block data.
__global__ __launch_bounds__(256) void dp_k(const unsigned short* __restrict__ cnt16,
                                            unsigned* __restrict__ packed,
                                            unsigned* __restrict__ rowptr,
                                            unsigned* __restrict__ flags) {
    __shared__ unsigned wsum[4];
    __shared__ unsigned excl_s;
    int t = threadIdx.x, b = blockIdx.x;
    int lane = t & 63, wv = t >> 6;
    int dst = b * 256 + t;
    unsigned deg = 0;
    if (dst < NN) {
        unsigned run = 0;
        #pragma unroll 5
        for (int r = 0; r < NR; ++r) {
            unsigned c = cnt16[(size_t)r * NN + dst];
            F16Bits fb; fb.f = (_Float16)(c ? 1.0f / (float)c : 0.0f);
            packed[(size_t)r * NN + dst] = (run & 0xFFFFu) | ((unsigned)fb.u << 16);
            run += c;
        }
        deg = run;
    }
    unsigned s = deg;                      // inclusive wave scan
    #pragma unroll
    for (int off = 1; off < 64; off <<= 1) {
        unsigned n = __shfl_up(s, off);
        if (lane >= off) s += n;
    }
    if (lane == 63) wsum[wv] = s;
    __syncthreads();
    unsigned waveoff = 0;
    if (wv > 0) waveoff += wsum[0];
    if (wv > 1) waveoff += wsum[1];
    if (wv > 2) waveoff += wsum[2];
    unsigned blockT = wsum[0] + wsum[1] + wsum[2] + wsum[3];
    unsigned local_excl = waveoff + s - deg;
    if (t == 0) {
        if (b == 0) {
            excl_s = 0;
            atomicExch(&flags[0], 0x80000000u | blockT);     // state 2 (inclusive)
        } else {
            atomicExch(&flags[b], 0x40000000u | blockT);     // state 1 (aggregate)
            unsigned ex = 0;
            int p = b - 1;
            while (p >= 0) {
                unsigned f = atomicAdd(&flags[p], 0u);
                unsigned st = f >> 30;
                if (st == 0) continue;                        // spin
                ex += f & 0x3FFFFFFFu;
                if (st >= 2) break;
                --p;
            }
            excl_s = ex;
            atomicExch(&flags[b], 0x80000000u | (ex + blockT));
        }
    }
    __syncthreads();
    unsigned ex = excl_s;
    if (dst < NN) rowptr[dst] = ex + local_excl;
    if (b == (int)gridDim.x - 1 && t == 0) rowptr[NN] = ex + blockT;
}

// ---------------------------------------------------------------------------
// Layer-1 messages via MFMA, finalize fused in the prologue (no pedges).
// One wave = 64 edges of ONE relation (and one 4096-src window) = 4 tiles of
// 16 edges; 4x mfma per tile. MFMA C (edge = quad*4+i, channel = col/col+16)
// is transposed IN-WAVE so each store instr writes 16 full 64-B rows.
__global__ __launch_bounds__(256) void msg1_k(const __half* __restrict__ xh,
                                              const __half* __restrict__ W1f,
                                              const unsigned* __restrict__ rsorted,
                                              const unsigned short* __restrict__ rank16,
                                              const unsigned* __restrict__ packed,
                                              const unsigned* __restrict__ rowptr,
                                              const int* __restrict__ chunkrel,
                                              __half* __restrict__ msg) {
    int tid = threadIdx.x;
    int lane = tid & 63;
    int wave = (blockIdx.x * 256 + tid) >> 6;
    if (wave >= NCHUNK) return;
    int e = (wave << 6) + lane;
    int rel = __builtin_amdgcn_readfirstlane(chunkrel[wave]);   // wave-uniform
    unsigned v = rsorted[e];
    unsigned dst = v >> 16;
    int src = 0, drow = NE;
    float sc = 0.f;
    if (dst < NN) {
        unsigned pk = packed[(size_t)rel * NN + dst];
        unsigned dpos = rowptr[dst] + (pk & 0xFFFFu) + (unsigned)rank16[e];
        src = v & 0xFFFF;
        F16Bits fb; fb.u = (unsigned short)(pk >> 16);
        sc = (float)fb.f;
        drow = (int)dpos;
    }
    const uint4* __restrict__ wf = (const uint4*)W1f + (size_t)rel * 256;
    ABFrag b00, b01, b10, b11;
    b00.u = wf[0 * 64 + lane];
    b01.u = wf[1 * 64 + lane];
    b10.u = wf[2 * 64 + lane];
    b11.u = wf[3 * 64 + lane];
    int quad = lane >> 4, col = lane & 15;
    ABFrag a0[4], a1[4];
    #pragma unroll
    for (int tl = 0; tl < 4; ++tl) {
        int s = __shfl(src, tl * 16 + col);
        const uint4* __restrict__ xp = (const uint4*)(xh + (size_t)s * INC) + quad;
        a0[tl].u = xp[0];
        a1[tl].u = xp[4];
    }
    int eloc = lane >> 2, wq = lane & 3, isel = eloc & 3;
    #pragma unroll
    for (int tl = 0; tl < 4; ++tl) {
        f32x4 acc0 = {0.f, 0.f, 0.f, 0.f}, acc1 = {0.f, 0.f, 0.f, 0.f};
        acc0 = __builtin_amdgcn_mfma_f32_16x16x32_f16(a0[tl].f, b00.f, acc0, 0, 0, 0);
        acc0 = __builtin_amdgcn_mfma_f32_16x16x32_f16(a1[tl].f, b10.f, acc0, 0, 0, 0);
        acc1 = __builtin_amdgcn_mfma_f32_16x16x32_f16(a0[tl].f, b01.f, acc1, 0, 0, 0);
        acc1 = __builtin_amdgcn_mfma_f32_16x16x32_f16(a1[tl].f, b11.f, acc1, 0, 0, 0);
        unsigned um[4];
        #pragma unroll
        for (int i = 0; i < 4; ++i) {
            int ee = tl * 16 + quad * 4 + i;          // edge owning this D row
            float si = __shfl(sc, ee);
            union { __half2 h; unsigned u; } cv;
            cv.h = __floats2half2_rn(acc0[i] * si, acc1[i] * si);
            um[i] = cv.u;                             // word col of edge ee
        }
        // in-wave 16x16 dword transpose: lane (eloc,wq) gathers words
        // 4wq..4wq+3 of edge tl*16+eloc from lanes (eloc>>2)*16 + w.
        unsigned w4[4];
        #pragma unroll
        for (int q = 0; q < 4; ++q) {
            int srcl = ((lane >> 4) << 4) + (wq << 2) + q;
            unsigned t0 = __shfl(um[0], srcl);
            unsigned t1 = __shfl(um[1], srcl);
            unsigned t2 = __shfl(um[2], srcl);
            unsigned t3 = __shfl(um[3], srcl);
            w4[q] = (isel == 0) ? t0 : (isel == 1) ? t1 : (isel == 2) ? t2 : t3;
        }
        int dr = __shfl(drow, tl * 16 + eloc);
        ((uint4*)(msg + (size_t)dr * HIDC))[wq] =
            make_uint4(w4[0], w4[1], w4[2], w4[3]);
    }
}

// Layer-2 messages via MFMA (32 -> 16), record re-derived inline (no pedges).
// 1 MFMA per 16-edge tile; word c of a row = half2{ch c, ch c+8} via the
// shfl_xor fold; in-wave transpose packs 32-B rows (lanes 2e,2e+1).
__global__ __launch_bounds__(256) void msg2_k(const __half* __restrict__ hh,
                                              const __half* __restrict__ W2f,
                                              const unsigned* __restrict__ rsorted,
                                              const unsigned short* __restrict__ rank16,
                                              const unsigned* __restrict__ packed,
                                              const unsigned* __restrict__ rowptr,
                                              const int* __restrict__ chunkrel,
                                              __half* __restrict__ msg) {
    int tid = threadIdx.x;
    int lane = tid & 63;
    int wave = (blockIdx.x * 256 + tid) >> 6;
    if (wave >= NCHUNK) return;
    int e = (wave << 6) + lane;
    int rel = __builtin_amdgcn_readfirstlane(chunkrel[wave]);
    unsigned v = rsorted[e];
    unsigned dst = v >> 16;
    int src = 0, drow = NE;
    float sc = 0.f;
    if (dst < NN) {
        unsigned pk = packed[(size_t)rel * NN + dst];
        unsigned dpos = rowptr[dst] + (pk & 0xFFFFu) + (unsigned)rank16[e];
        src = v & 0xFFFF;
        F16Bits fb; fb.u = (unsigned short)(pk >> 16);
        sc = (float)fb.f;
        drow = (int)dpos;
    }
    ABFrag bf;
    bf.u = ((const uint4*)W2f + (size_t)rel * 64)[lane];
    int quad = lane >> 4, col = lane & 15;
    ABFrag a[4];
    #pragma unroll
    for (int tl = 0; tl < 4; ++tl) {
        int s = __shfl(src, tl * 16 + col);
        a[tl].u = *((const uint4*)(hh + (size_t)s * HIDC) + quad);
    }
    int isel2 = (lane >> 1) & 3;
    #pragma unroll
    for (int tl = 0; tl < 4; ++tl) {
        f32x4 acc = {0.f, 0.f, 0.f, 0.f};
        acc = __builtin_amdgcn_mfma_f32_16x16x32_f16(a[tl].f, bf.f, acc, 0, 0, 0);
        unsigned um[4];
        #pragma unroll
        for (int i = 0; i < 4; ++i) {
            int ee = tl * 16 + quad * 4 + i;
            float si = __shfl(sc, ee);
            float vv = acc[i] * si;
            float p  = __shfl_xor(vv, 8);            // partner channel col^8
            union { __half2 h; unsigned u; } cv;
            cv.h = __floats2half2_rn(vv, p);         // {ch col, ch col+8}
            um[i] = cv.u;                            // valid on lanes col<8
        }
        // transpose: lane (e2=lane>>1, wq2=lane&1) gathers words 4wq2..4wq2+3
        // of edge tl*16+e2 from lanes (e2>>2)*16 + w (w<8 -> col<8 sources).
        unsigned w4[4];
        #pragma unroll
        for (int q = 0; q < 4; ++q) {
            int srcl = (((lane >> 3) << 4) + ((lane & 1) << 2) + q) & 63;
            unsigned t0 = __shfl(um[0], srcl);
            unsigned t1 = __shfl(um[1], srcl);
            unsigned t2 = __shfl(um[2], srcl);
            unsigned t3 = __shfl(um[3], srcl);
            w4[q] = (isel2 == 0) ? t0 : (isel2 == 1) ? t1 : (isel2 == 2) ? t2 : t3;
        }
        int dr = __shfl(drow, (tl * 16 + (lane >> 1)) & 63);
        if (lane < 32) {
            ((uint4*)(msg + (size_t)dr * OUTC))[lane & 1] =
                make_uint4(w4[0], w4[1], w4[2], w4[3]);
        }
    }
}

// ---------------------------------------------------------------------------
// Fused gather + node update 1: h = relu(sum(msg rows) + x @ root1 + b1), f16
// out. One wave per node. Lane (g = lane>>2, j = lane&3): loop k = k0+g step
// 16, uint4 load of row-quad j -> wave trip reads 16 contiguous rows (1 KB).
// Root term: in-channels 4g..4g+3 x out-words 4j..4j+3 with weights in
// REGISTERS from pre-permuted rootp1 (no LDS). Reduce over g via shfl_xor;
// lanes g==0 write the hh row as 4 coalesced uint4.
__global__ __launch_bounds__(256) void gather1_k(const __half* __restrict__ xh,
                                                 const float2* __restrict__ rootp1,
                                                 const float2* __restrict__ b1p,
                                                 const __half* __restrict__ msg,
                                                 const unsigned* __restrict__ rowptr,
                                                 __half* __restrict__ hh) {
    int tid = threadIdx.x;
    int lane = tid & 63;
    int wid = (blockIdx.x * 256 + tid) >> 6;   // node id; grid exact
    int g = lane >> 2, j = lane & 3;
    unsigned k0 = rowptr[wid], k1 = rowptr[wid + 1];
    // per-lane root weights: rw[i][q] = rootp1[(4g+i)*16 + 4j+q]
    float2 rw[4][4];
    #pragma unroll
    for (int i = 0; i < 4; ++i) {
        const float4* __restrict__ rp =
            (const float4*)rootp1 + ((4 * g + i) << 3) + 2 * j;
        float4 u0 = rp[0], u1 = rp[1];
        rw[i][0] = make_float2(u0.x, u0.y);
        rw[i][1] = make_float2(u0.z, u0.w);
        rw[i][2] = make_float2(u1.x, u1.y);
        rw[i][3] = make_float2(u1.z, u1.w);
    }
    float acc[8] = {0.f, 0.f, 0.f, 0.f, 0.f, 0.f, 0.f, 0.f};
    for (unsigned k = k0 + g; k < k1; k += 16) {
        uint4 v = ((const uint4*)(msg + (size_t)k * HIDC))[j];
        union { unsigned u; __half2 h; } c0, c1, c2, c3;
        c0.u = v.x; c1.u = v.y; c2.u = v.z; c3.u = v.w;
        float2 f0 = __half22float2(c0.h), f1 = __half22float2(c1.h);
        float2 f2 = __half22float2(c2.h), f3 = __half22float2(c3.h);
        acc[0] += f0.x; acc[1] += f0.y;
        acc[2] += f1.x; acc[3] += f1.y;
        acc[4] += f2.x; acc[5] += f2.y;
        acc[6] += f3.x; acc[7] += f3.y;
    }
    // root term: x channels 4g..4g+3
    union { uint2 u; __half2 h[2]; } xv;
    xv.u = ((const uint2*)(xh + (size_t)wid * INC))[g];
    float2 xa = __half22float2(xv.h[0]), xb = __half22float2(xv.h[1]);
    float xs[4] = { xa.x, xa.y, xb.x, xb.y };
    #pragma unroll
    for (int i = 0; i < 4; ++i) {
        #pragma unroll
        for (int q = 0; q < 4; ++q) {
            acc[2 * q]     = fmaf(xs[i], rw[i][q].x, acc[2 * q]);
            acc[2 * q + 1] = fmaf(xs[i], rw[i][q].y, acc[2 * q + 1]);
        }
    }
    #pragma unroll
    for (int off = 4; off < 64; off <<= 1) {
        #pragma unroll
        for (int q = 0; q < 8; ++q) acc[q] += __shfl_xor(acc[q], off);
    }
    if (g == 0) {
        const float4* __restrict__ bp4 = (const float4*)b1p;
        float4 bb0 = bp4[2 * j], bb1 = bp4[2 * j + 1];
        float2 bq[4] = { make_float2(bb0.x, bb0.y), make_float2(bb0.z, bb0.w),
                         make_float2(bb1.x, bb1.y), make_float2(bb1.z, bb1.w) };
        unsigned um[4];
        #pragma unroll
        for (int q = 0; q < 4; ++q) {
            float vx = acc[2 * q] + bq[q].x, vy = acc[2 * q + 1] + bq[q].y;
            union { __half2 h2; unsigned u; } cv;
            cv.h2 = __floats2half2_rn(vx > 0.f ? vx : 0.f, vy > 0.f ? vy : 0.f);
            um[q] = cv.u;
        }
        ((uint4*)(hh + (size_t)wid * HIDC))[j] = make_uint4(um[0], um[1], um[2], um[3]);
    }
}

// Fused gather + node update 2: out = sum(msg rows) + h @ root2 + b2 (f32 out).
// Lane (g = lane>>1, j = lane&1): loop k = k0+g step 32 (wave trip = 32 rows
// / 1 KB). Root: in-channel g (natural index; hh word (g&15) half (g>>4)),
// weights in registers from rootp2. Reduce over g; lanes g==0 write 2 float4.
__global__ __launch_bounds__(256) void gather2_k(const __half* __restrict__ hh,
                                                 const float2* __restrict__ rootp2,
                                                 const float* __restrict__ b2,
                                                 const __half* __restrict__ msg,
                                                 const unsigned* __restrict__ rowptr,
                                                 float* __restrict__ out) {
    int tid = threadIdx.x;
    int lane = tid & 63;
    int wid = (blockIdx.x * 256 + tid) >> 6;
    int g = lane >> 1, j = lane & 1;
    unsigned k0 = rowptr[wid], k1 = rowptr[wid + 1];
    // rw[q] = rootp2[g*8 + 4j+q] = {root2[g][4j+q], root2[g][4j+q+8]}
    const float4* __restrict__ rp = (const float4*)rootp2 + (g << 2) + 2 * j;
    float4 u0 = rp[0], u1 = rp[1];
    float2 rw[4] = { make_float2(u0.x, u0.y), make_float2(u0.z, u0.w),
                     make_float2(u1.x, u1.y), make_float2(u1.z, u1.w) };
    float acc[8] = {0.f, 0.f, 0.f, 0.f, 0.f, 0.f, 0.f, 0.f};
    for (unsigned k = k0 + g; k < k1; k += 32) {
        uint4 v = ((const uint4*)(msg + (size_t)k * OUTC))[j];
        union { unsigned u; __half2 h; } c0, c1, c2, c3;
        c0.u = v.x; c1.u = v.y; c2.u = v.z; c3.u = v.w;
        float2 f0 = __half22float2(c0.h), f1 = __half22float2(c1.h);
        float2 f2 = __half22float2(c2.h), f3 = __half22float2(c3.h);
        acc[0] += f0.x; acc[1] += f0.y;
        acc[2] += f1.x; acc[3] += f1.y;
        acc[4] += f2.x; acc[5] += f2.y;
        acc[6] += f3.x; acc[7] += f3.y;
    }
    // h channel g: hh word (g&15) = {ch g&15, ch (g&15)+16}
    unsigned hw = ((const unsigned*)(hh + (size_t)wid * HIDC))[g & 15];
    union { unsigned u; __half2 h; } hc; hc.u = hw;
    float2 hf = __half22float2(hc.h);
    float hv = (g < 16) ? hf.x : hf.y;
    #pragma unroll
    for (int q = 0; q < 4; ++q) {
        acc[2 * q]     = fmaf(hv, rw[q].x, acc[2 * q]);
        acc[2 * q + 1] = fmaf(hv, rw[q].y, acc[2 * q + 1]);
    }
    #pragma unroll
    for (int off = 2; off < 64; off <<= 1) {
        #pragma unroll
        for (int q = 0; q < 8; ++q) acc[q] += __shfl_xor(acc[q], off);
    }
    if (g == 0) {
        float* __restrict__ orow = out + (size_t)wid * OUTC;
        float4 ba = ((const float4*)b2)[j];        // channels 4j..4j+3
        float4 bb = ((const float4*)b2)[j + 2];    // channels 4j+8..4j+11
        ((float4*)orow)[j] = make_float4(acc[0] + ba.x, acc[2] + ba.y,
                                         acc[4] + ba.z, acc[6] + ba.w);
        ((float4*)orow)[j + 2] = make_float4(acc[1] + bb.x, acc[3] + bb.y,
                                             acc[5] + bb.z, acc[7] + bb.w);
    }
}

// ---------------------------------------------------------------------------
extern "C" void kernel_launch(void* const* d_in, const int* in_sizes, int n_in,
                              void* d_out, int out_size, void* d_ws, size_t ws_size,
                              hipStream_t stream) {
    const float* x     = (const float*)d_in[0];
    const int*   ei    = (const int*)d_in[1];   // [2, NE]
    const int*   et    = (const int*)d_in[2];   // [NE]
    const float* W1    = (const float*)d_in[3];
    const float* root1 = (const float*)d_in[4];
    const float* b1    = (const float*)d_in[5];
    const float* W2    = (const float*)d_in[6];
    const float* root2 = (const float*)d_in[7];
    const float* b2    = (const float*)d_in[8];
    float* out = (float*)d_out;

    char* ws = (char*)d_ws;
    size_t o = 0;
    auto alloc = [&](size_t bytes) -> char* {
        char* p = ws + o;
        o = (o + bytes + 255) & ~(size_t)255;
        return p;
    };
    // Everything initialized inside the kernels (rsorted pad init + flag
    // zeroing live in preph_k). No memset node.
    unsigned* rsorted = (unsigned*)alloc((size_t)MAXE * 4);        // 4.95 MB
    unsigned* flagbuf = (unsigned*)alloc(256 * 4);    // [32..227]=dp flags
    unsigned* ghist   = (unsigned*)alloc((size_t)NBKT * NB * 4);   // 686 KB
    unsigned* bbase   = (unsigned*)alloc((size_t)NBKT * NB * 4);   // 686 KB
    unsigned* btot    = (unsigned*)alloc((size_t)NBKT * 4);
    unsigned* gbase   = (unsigned*)alloc((size_t)(NBKT + 1) * 4);
    int*      chunkrel= (int*)     alloc((size_t)NCHUNK * 4);
    unsigned short* rank16 = (unsigned short*)alloc((size_t)MAXE * 2);
    unsigned short* cnt16  = (unsigned short*)alloc((size_t)NR * NN * 2); // 4.5 MB
    unsigned* packed  = (unsigned*)alloc((size_t)NR * NN * 4);     // 9.0 MB
    unsigned* rowptr  = (unsigned*)alloc(((size_t)NN + 1) * 4);
    __half*   W1f     = (__half*)  alloc((size_t)NR * 2048 * 2);
    __half*   W2f     = (__half*)  alloc((size_t)NR * 512 * 2);
    __half*   xh      = (__half*)  alloc((size_t)NN * INC * 2);    // 6.4 MB
    __half*   hh      = (__half*)  alloc((size_t)NN * HIDC * 2);   // 3.2 MB
    float2*   rootp1  = (float2*)  alloc(1024 * 8);                // 8 KB
    float2*   rootp2  = (float2*)  alloc(256 * 8);                 // 2 KB
    float2*   b1p     = (float2*)  alloc(16 * 8);
    // msg buffers alias: msg1 (f16, 64-B rows) fully consumed by gather1
    // before msg2 (f16, 32-B rows) is produced.
    char*     msgraw  = alloc(((size_t)NE + 1) * 64);              // 76.9 MB
    __half*   msg1    = (__half*)msgraw;
    __half*   msg2    = (__half*)msgraw;

    int prep_grid = NN * INC / 2 / 256;   // 6250 >= NB, covers all prep work
    preph_k   <<<prep_grid, 256, 0, stream>>>(W1, W2, x, ei, et, root1, root2, b1,
                                              W1f, W2f, xh, rootp1, rootp2, b1p,
                                              ghist, rsorted, flagbuf);
    scanA_k   <<<NBKT, 64, 0, stream>>>(ghist, bbase, btot);
    scanB_k   <<<1, 1024, 0, stream>>>(btot, gbase, chunkrel);
    scat_k    <<<NB, 1024, 0, stream>>>(ei, et, bbase, gbase, rsorted);
    relcnt_k  <<<4 * NR, 1024, 0, stream>>>(rsorted, gbase, cnt16, rank16);
    dp_k      <<<NTILE, 256, 0, stream>>>(cnt16, packed, rowptr, flagbuf + 32);
    msg1_k    <<<(MAXE + 255) / 256, 256, 0, stream>>>(xh, W1f, rsorted, rank16,
                                                       packed, rowptr, chunkrel,
                                                       msg1);
    gather1_k <<<NN * 64 / 256, 256, 0, stream>>>(xh, rootp1, b1p, msg1, rowptr, hh);
    msg2_k    <<<(MAXE + 255) / 256, 256, 0, stream>>>(hh, W2f, rsorted, rank16,
                                                       packed, rowptr, chunkrel,
                                                       msg2);
    gather2_k <<<NN * 64 / 256, 256, 0, stream>>>(hh, rootp2, b2, msg2, rowptr, out);
}

// Round 9
// 294.196 us; speedup vs baseline: 1.0556x; 1.0556x over previous
//
#include <hip/hip_runtime.h>
#include <hip/hip_fp16.h>
#include <cstdint>
#include <cstddef>

// Problem constants (match reference setup_inputs)
#define NN   50000      // nodes  (< 65536: src/dst fit 16 bits)
#define NE   1200000    // edges
#define NR   45         // relations
#define INC  64
#define HIDC 32
#define OUTC 16
// Padded edge capacity: each relation bucket padded to multiple of 64 so every
// wave's 64 edges share one relation. NE + NR*64, itself a multiple of 64.
#define MAXE 1202880
#define NCHUNK (MAXE/64)                // 18795
// relation counting-sort blocking
#define EPB 4096
#define NB  ((NE + EPB - 1) / EPB)      // 293 blocks
// relcnt: 4 dst-quarters per relation; 6250 LDS words x two u16 = 12500 dsts
#define QDW 6250
#define QDD 12500                       // 4*12500 = 50000 = NN exactly
// dp_k lookback tiles (256 dsts each)
#define NTILE ((NN + 255) / 256)        // 196

// Message rows are stored CHANNEL-INTERLEAVED (no LDS transpose needed):
//   layer-1 row word c (c=0..15) = half2{ ch c, ch c+16 }
//   layer-2 row word c (c=0..7)  = half2{ ch c, ch c+8  }
// hh is stored with the layer-1 interleave: stored element s <-> channel
// (s>>1) + (s&1)*16. W2f bakes the inverse permutation into its k index.
// Gathers read msg rows 16 B/lane and keep root weights in REGISTERS.
// finalize is FUSED into msg1 (builds records inline, writes pedges as a
// side product); msg2 reads pedges linearly (R8 showed re-deriving in msg2
// regresses: random packed gather twice).
// msg1/msg2 process TWO 64-edge chunks per wave in a straight-line body:
// R8 proved msg1 is LATENCY-bound (duration invariant to bytes/segments/
// locality), so doubling independent memory chains per wave is the lever.
// NOTE (round 2): nontemporal loads/stores REGRESSED badly. Default policy.
// NOTE (rounds 5+8): (src-group, rel) bucketing for gather locality nulled
// twice (FETCH unchanged) -> 45 relation buckets, simple scat.

typedef _Float16 f16x8 __attribute__((ext_vector_type(8)));
typedef float    f32x4 __attribute__((ext_vector_type(4)));

union F16Bits { unsigned short u; _Float16 f; };
union ABFrag   { uint4 u; f16x8 f; };

// ---------------------------------------------------------------------------
// Fused prep + relation histogram + buffer init. All blocks do striped prep
// work (MFMA B-fragments in exact lane order + x f32->f16 cast + rsorted pad
// init + dp-flag zeroing + permuted root/bias tables for the gathers); the
// first NB blocks also build the per-block 45-bin relation histogram
// (4 per-wave LDS sub-histograms). ghist layout is TRANSPOSED: [rel][NB].
//   B[k][n] fragment for 16x16x32: lane holds k=(lane>>4)*8+j, n=lane&15.
__global__ __launch_bounds__(256) void preph_k(const float* __restrict__ W1,
                                               const float* __restrict__ W2,
                                               const float* __restrict__ x,
                                               const int* __restrict__ ei,
                                               const int* __restrict__ et,
                                               const float* __restrict__ root1,
                                               const float* __restrict__ root2,
                                               const float* __restrict__ b1,
                                               __half* __restrict__ W1f,
                                               __half* __restrict__ W2f,
                                               __half* __restrict__ xh,
                                               float2* __restrict__ rootp1,
                                               float2* __restrict__ rootp2,
                                               float2* __restrict__ b1p,
                                               unsigned* __restrict__ ghist,
                                               unsigned* __restrict__ rsorted,
                                               unsigned* __restrict__ flagbuf) {
    __shared__ unsigned lh[4 * 48];   // 4 per-wave sub-histograms (48: bank pad)
    int t = threadIdx.x, b = blockIdx.x;
    int wv = t >> 6;
    if (t < 192) lh[t] = 0;
    __syncthreads();
    if (b < NB) {
        #pragma unroll
        for (int it = 0; it < EPB / 256; ++it) {
            int e = b * EPB + it * 256 + t;
            if (e < NE) {
                int r = et[e], src = ei[e], dst = ei[NE + e];
                if ((unsigned)r < NR && (unsigned)src < NN && (unsigned)dst < NN)
                    atomicAdd(&lh[wv * 48 + r], 1u);
            }
        }
    }
    __syncthreads();
    if (b < NB && t < NR)
        ghist[t * NB + b] = lh[t] + lh[48 + t] + lh[96 + t] + lh[144 + t];
    int g = b * 256 + t;
    int gthreads = gridDim.x * 256;
    // pad-sentinel init (replaces hipMemsetAsync node)
    for (int i = g; i < MAXE; i += gthreads) rsorted[i] = 0xFFFFFFFFu;
    if (b == 0) flagbuf[t] = 0;     // words 32..227: dp lookback flags
    if (g < NR * 2048) {
        int r = g >> 11, rem = g & 2047;
        int kb = rem >> 10, nb = (rem >> 9) & 1;
        int lane = (rem >> 3) & 63, j = rem & 7;
        int k = kb * 32 + (lane >> 4) * 8 + j;
        int n = nb * 16 + (lane & 15);
        W1f[g] = __float2half(W1[(r * INC + k) * HIDC + n]);
    }
    if (g < NR * 512) {
        int r = g >> 9, rem = g & 511;
        int lane = (rem >> 3) & 63, j = rem & 7;
        int k = (lane >> 4) * 8 + j;          // stored k index s
        int kc = (k >> 1) + ((k & 1) << 4);   // channel = perm(s) to match hh
        int n = lane & 15;
        W2f[g] = __float2half(W2[(r * HIDC + kc) * OUTC + n]);
    }
    if (g < NN * INC / 2) {
        float2 f = ((const float2*)x)[g];
        union { __half2 h; unsigned u; } cv;
        cv.h = __floats2half2_rn(f.x, f.y);
        ((unsigned*)xh)[g] = cv.u;
    }
    // permuted gather tables: rootp1[in*16+w] = {root1[in][w], root1[in][w+16]}
    if (g < 1024) {
        int in = g >> 4, w = g & 15;
        rootp1[g] = make_float2(root1[in * HIDC + w], root1[in * HIDC + w + 16]);
    }
    if (g < 256) {
        int in = g >> 3, w = g & 7;
        rootp2[g] = make_float2(root2[in * OUTC + w], root2[in * OUTC + w + 8]);
    }
    if (g < 16) b1p[g] = make_float2(b1[g], b1[g + 16]);
}

// ---------------------------------------------------------------------------
// Scatter into relation buckets — NO serial scan phase, NO spin. Each block
// derives its own deterministic base from the L2-resident per-relation
// histogram row: lbase[r] = relbase[r] + sum_{b<bx} ghist[r][b] (45 lanes
// stream NB sequential words each). Block 0 additionally writes rngs +
// chunkrel (consumed only by later dispatches). Pads keep the sentinel.
__global__ __launch_bounds__(1024) void scat_k(const int* __restrict__ ei,
                                               const int* __restrict__ et,
                                               const unsigned* __restrict__ ghist,
                                               unsigned* __restrict__ rngs,
                                               int* __restrict__ chunkrel,
                                               unsigned* __restrict__ rsorted) {
    __shared__ unsigned reltot[NR];       // column totals
    __shared__ unsigned mypart[NR];       // partial prefix up to this block
    __shared__ unsigned relbase[NR + 1];  // padded bucket bases
    __shared__ unsigned lbase[NR], lcur[NR];
    int t = threadIdx.x, bx = blockIdx.x;
    if (t < NR) {
        unsigned total = 0, part = 0;
        const unsigned* __restrict__ row = ghist + t * NB;
        for (int b = 0; b < NB; ++b) {
            if (b == bx) part = total;
            total += row[b];
        }
        reltot[t] = total;
        mypart[t] = part;
        lcur[t] = 0;
    }
    __syncthreads();
    if (t == 0) {
        unsigned acc = 0;
        for (int r = 0; r < NR; ++r) {
            relbase[r] = acc;
            acc += ((reltot[r] + 63u) >> 6) << 6;
        }
        relbase[NR] = acc;
    }
    __syncthreads();
    if (t < NR) lbase[t] = relbase[t] + mypart[t];
    __syncthreads();
    #pragma unroll
    for (int it = 0; it < EPB / 1024; ++it) {
        int e = bx * EPB + it * 1024 + t;
        if (e < NE) {
            int r = et[e], src = ei[e], dst = ei[NE + e];
            if ((unsigned)r < NR && (unsigned)src < NN && (unsigned)dst < NN) {
                unsigned local = atomicAdd(&lcur[r], 1u);
                rsorted[lbase[r] + local] = (unsigned)src | ((unsigned)dst << 16);
            }
        }
    }
    if (bx == 0) {
        if (t < NR) {
            rngs[2 * t]     = relbase[t];
            rngs[2 * t + 1] = relbase[t] + reltot[t];
        }
        for (int c = t; c < NCHUNK; c += 1024) {
            unsigned pos = (unsigned)c << 6;
            int lo = 0, hi = NR - 1;
            while (lo < hi) {
                int mid = (lo + hi + 1) >> 1;
                if (relbase[mid] <= pos) lo = mid; else hi = mid - 1;
            }
            chunkrel[c] = lo;
        }
    }
}

// Per-relation dst counts + per-edge rank in ONE pass (the atomic's old value
// is the rank; the final LDS word is the count). Four dst-quarters per
// relation (25 KB LDS) -> 180 blocks; the 4 co-scans of a bucket share L2.
__global__ __launch_bounds__(1024) void relcnt_k(const unsigned* __restrict__ rsorted,
                                                 const unsigned* __restrict__ rngs,
                                                 unsigned short* __restrict__ cnt16,
                                                 unsigned short* __restrict__ rank16) {
    __shared__ unsigned lds[QDW];     // 25000 B
    int r = blockIdx.x >> 2, q = blockIdx.x & 3, t = threadIdx.x;
    unsigned base = rngs[2 * r], end = rngs[2 * r + 1];
    unsigned dlo = q * QDD, dhi = dlo + QDD;   // 4*12500 = NN exactly
    for (int w = t; w < QDW; w += 1024) lds[w] = 0;
    __syncthreads();
    for (unsigned s = base + t; s < end; s += 1024) {
        unsigned d = rsorted[s] >> 16;
        if (d >= dlo && d < dhi) {
            unsigned off = d - dlo;
            unsigned old = atomicAdd(&lds[off >> 1], (off & 1) ? 0x10000u : 1u);
            rank16[s] = (unsigned short)((off & 1) ? (old >> 16) : (old & 0xFFFFu));
        }
    }
    __syncthreads();
    unsigned* __restrict__ cp = (unsigned*)(cnt16 + (size_t)r * NN + dlo);
    for (int w = t; w < QDW; w += 1024) cp[w] = lds[w];
}

// ---------------------------------------------------------------------------
// Fused drel + dprefix via decoupled lookback. Tile = 256 dsts. Per dst:
// relation-prefix offsets + f16 inverse counts packed into one word per
// (r,dst); block-scan of degrees; lookback chain carries block sums INSIDE
// the atomic flag word {state:2 | sum:30} -> no non-atomic cross-block data.
__global__ __launch_bounds__(256) void dp_k(const unsigned short* __restrict__ cnt16,
                                            unsigned* __restrict__ packed,
                                            unsigned* __restrict__ rowptr,
                                            unsigned* __restrict__ flags) {
    __shared__ unsigned wsum[4];
    __shared__ unsigned excl_s;
    int t = threadIdx.x, b = blockIdx.x;
    int lane = t & 63, wv = t >> 6;
    int dst = b * 256 + t;
    unsigned deg = 0;
    if (dst < NN) {
        unsigned run = 0;
        #pragma unroll 5
        for (int r = 0; r < NR; ++r) {
            unsigned c = cnt16[(size_t)r * NN + dst];
            F16Bits fb; fb.f = (_Float16)(c ? 1.0f / (float)c : 0.0f);
            packed[(size_t)r * NN + dst] = (run & 0xFFFFu) | ((unsigned)fb.u << 16);
            run += c;
        }
        deg = run;
    }
    unsigned s = deg;                      // inclusive wave scan
    #pragma unroll
    for (int off = 1; off < 64; off <<= 1) {
        unsigned n = __shfl_up(s, off);
        if (lane >= off) s += n;
    }
    if (lane == 63) wsum[wv] = s;
    __syncthreads();
    unsigned waveoff = 0;
    if (wv > 0) waveoff += wsum[0];
    if (wv > 1) waveoff += wsum[1];
    if (wv > 2) waveoff += wsum[2];
    unsigned blockT = wsum[0] + wsum[1] + wsum[2] + wsum[3];
    unsigned local_excl = waveoff + s - deg;
    if (t == 0) {
        if (b == 0) {
            excl_s = 0;
            atomicExch(&flags[0], 0x80000000u | blockT);     // state 2 (inclusive)
        } else {
            atomicExch(&flags[b], 0x40000000u | blockT);     // state 1 (aggregate)
            unsigned ex = 0;
            int p = b - 1;
            while (p >= 0) {
                unsigned f = atomicAdd(&flags[p], 0u);
                unsigned st = f >> 30;
                if (st == 0) continue;                        // spin
                ex += f & 0x3FFFFFFFu;
                if (st >= 2) break;
                --p;
            }
            excl_s = ex;
            atomicExch(&flags[b], 0x80000000u | (ex + blockT));
        }
    }
    __syncthreads();
    unsigned ex = excl_s;
    if (dst < NN) rowptr[dst] = ex + local_excl;
    if (b == (int)gridDim.x - 1 && t == 0) rowptr[NN] = ex + blockT;
}

// ---------------------------------------------------------------------------
// Layer-1 messages via MFMA, finalize fused in the prologue, TWO chunks per
// wave (A,B) in one straight-line body so chunk B's record/fragment loads
// overlap chunk A's dependency chain (R8: msg1 is latency-bound). Each chunk:
// 64 edges of ONE relation = 4 tiles; per-edge record built inline from
// rsorted/rank16/packed/rowptr/chunkrel; pedges written as side product for
// msg2's linear read. MFMA C (edge = quad*4+i, channel = col/col+16) is
// transposed IN-WAVE so each store instr writes 16 full 64-B rows.
__global__ __launch_bounds__(256) void msg1_k(const __half* __restrict__ xh,
                                              const __half* __restrict__ W1f,
                                              const unsigned* __restrict__ rsorted,
                                              const unsigned short* __restrict__ rank16,
                                              const unsigned* __restrict__ packed,
                                              const unsigned* __restrict__ rowptr,
                                              const int* __restrict__ chunkrel,
                                              uint2* __restrict__ pedges,
                                              __half* __restrict__ msg) {
    int tid = threadIdx.x;
    int lane = tid & 63;
    int wv0 = (blockIdx.x * 256 + tid) >> 6;
    int waveA = wv0 << 1;
    if (waveA >= NCHUNK) return;
    bool hasB = (waveA + 1) < NCHUNK;
    int quad = lane >> 4, col = lane & 15;
    int eloc = lane >> 2, wq = lane & 3, isel = eloc & 3;
    int e0 = (waveA << 6) + lane, e1 = e0 + 64;

    // ---- record loads, both chunks (independent, issue together)
    int relA = __builtin_amdgcn_readfirstlane(chunkrel[waveA]);
    unsigned vA = rsorted[e0];
    unsigned rkA = rank16[e0];
    int relB = relA;
    unsigned vB = 0xFFFFFFFFu, rkB = 0;
    if (hasB) {
        relB = __builtin_amdgcn_readfirstlane(chunkrel[waveA + 1]);
        vB = rsorted[e1];
        rkB = rank16[e1];
    }
    // ---- derive records
    unsigned dstA = vA >> 16;
    int srcA = 0, drowA = NE; float scA = 0.f;
    uint2 peA = make_uint2(0u, 0x80000000u);
    if (dstA < NN) {
        unsigned pk = packed[(size_t)relA * NN + dstA];
        unsigned dpos = rowptr[dstA] + (pk & 0xFFFFu) + rkA;
        srcA = vA & 0xFFFF;
        F16Bits fb; fb.u = (unsigned short)(pk >> 16); scA = (float)fb.f;
        drowA = (int)dpos;
        peA = make_uint2((vA & 0xFFFFu) | (pk & 0xFFFF0000u),
                         dpos | ((unsigned)relA << 25));
    }
    unsigned dstB = vB >> 16;
    int srcB = 0, drowB = NE; float scB = 0.f;
    uint2 peB = make_uint2(0u, 0x80000000u);
    if (dstB < NN) {
        unsigned pk = packed[(size_t)relB * NN + dstB];
        unsigned dpos = rowptr[dstB] + (pk & 0xFFFFu) + rkB;
        srcB = vB & 0xFFFF;
        F16Bits fb; fb.u = (unsigned short)(pk >> 16); scB = (float)fb.f;
        drowB = (int)dpos;
        peB = make_uint2((vB & 0xFFFFu) | (pk & 0xFFFF0000u),
                         dpos | ((unsigned)relB << 25));
    }
    pedges[e0] = peA;
    if (hasB) pedges[e1] = peB;

    // ---- B fragments, both relations
    const uint4* __restrict__ wfA = (const uint4*)W1f + (size_t)relA * 256;
    const uint4* __restrict__ wfB = (const uint4*)W1f + (size_t)relB * 256;
    ABFrag bA00, bA01, bA10, bA11, bB00, bB01, bB10, bB11;
    bA00.u = wfA[0 * 64 + lane]; bA01.u = wfA[1 * 64 + lane];
    bA10.u = wfA[2 * 64 + lane]; bA11.u = wfA[3 * 64 + lane];
    bB00.u = wfB[0 * 64 + lane]; bB01.u = wfB[1 * 64 + lane];
    bB10.u = wfB[2 * 64 + lane]; bB11.u = wfB[3 * 64 + lane];

    // ---- A fragments, both chunks (8 independent gathers in flight)
    ABFrag a0A[4], a1A[4], a0B[4], a1B[4];
    #pragma unroll
    for (int tl = 0; tl < 4; ++tl) {
        int sA = __shfl(srcA, tl * 16 + col);
        int sB = __shfl(srcB, tl * 16 + col);
        const uint4* __restrict__ xpA = (const uint4*)(xh + (size_t)sA * INC) + quad;
        const uint4* __restrict__ xpB = (const uint4*)(xh + (size_t)sB * INC) + quad;
        a0A[tl].u = xpA[0]; a1A[tl].u = xpA[4];
        a0B[tl].u = xpB[0]; a1B[tl].u = xpB[4];
    }
    // ---- compute + transposed store, chunk A then chunk B
    #pragma unroll
    for (int tl = 0; tl < 4; ++tl) {
        f32x4 acc0 = {0.f, 0.f, 0.f, 0.f}, acc1 = {0.f, 0.f, 0.f, 0.f};
        acc0 = __builtin_amdgcn_mfma_f32_16x16x32_f16(a0A[tl].f, bA00.f, acc0, 0, 0, 0);
        acc0 = __builtin_amdgcn_mfma_f32_16x16x32_f16(a1A[tl].f, bA10.f, acc0, 0, 0, 0);
        acc1 = __builtin_amdgcn_mfma_f32_16x16x32_f16(a0A[tl].f, bA01.f, acc1, 0, 0, 0);
        acc1 = __builtin_amdgcn_mfma_f32_16x16x32_f16(a1A[tl].f, bA11.f, acc1, 0, 0, 0);
        unsigned um[4];
        #pragma unroll
        for (int i = 0; i < 4; ++i) {
            int ee = tl * 16 + quad * 4 + i;
            float si = __shfl(scA, ee);
            union { __half2 h; unsigned u; } cv;
            cv.h = __floats2half2_rn(acc0[i] * si, acc1[i] * si);
            um[i] = cv.u;
        }
        unsigned w4[4];
        #pragma unroll
        for (int q = 0; q < 4; ++q) {
            int srcl = ((lane >> 4) << 4) + (wq << 2) + q;
            unsigned t0 = __shfl(um[0], srcl);
            unsigned t1 = __shfl(um[1], srcl);
            unsigned t2 = __shfl(um[2], srcl);
            unsigned t3 = __shfl(um[3], srcl);
            w4[q] = (isel == 0) ? t0 : (isel == 1) ? t1 : (isel == 2) ? t2 : t3;
        }
        int dr = __shfl(drowA, tl * 16 + eloc);
        ((uint4*)(msg + (size_t)dr * HIDC))[wq] =
            make_uint4(w4[0], w4[1], w4[2], w4[3]);
    }
    #pragma unroll
    for (int tl = 0; tl < 4; ++tl) {
        f32x4 acc0 = {0.f, 0.f, 0.f, 0.f}, acc1 = {0.f, 0.f, 0.f, 0.f};
        acc0 = __builtin_amdgcn_mfma_f32_16x16x32_f16(a0B[tl].f, bB00.f, acc0, 0, 0, 0);
        acc0 = __builtin_amdgcn_mfma_f32_16x16x32_f16(a1B[tl].f, bB10.f, acc0, 0, 0, 0);
        acc1 = __builtin_amdgcn_mfma_f32_16x16x32_f16(a0B[tl].f, bB01.f, acc1, 0, 0, 0);
        acc1 = __builtin_amdgcn_mfma_f32_16x16x32_f16(a1B[tl].f, bB11.f, acc1, 0, 0, 0);
        unsigned um[4];
        #pragma unroll
        for (int i = 0; i < 4; ++i) {
            int ee = tl * 16 + quad * 4 + i;
            float si = __shfl(scB, ee);
            union { __half2 h; unsigned u; } cv;
            cv.h = __floats2half2_rn(acc0[i] * si, acc1[i] * si);
            um[i] = cv.u;
        }
        unsigned w4[4];
        #pragma unroll
        for (int q = 0; q < 4; ++q) {
            int srcl = ((lane >> 4) << 4) + (wq << 2) + q;
            unsigned t0 = __shfl(um[0], srcl);
            unsigned t1 = __shfl(um[1], srcl);
            unsigned t2 = __shfl(um[2], srcl);
            unsigned t3 = __shfl(um[3], srcl);
            w4[q] = (isel == 0) ? t0 : (isel == 1) ? t1 : (isel == 2) ? t2 : t3;
        }
        int dr = __shfl(drowB, tl * 16 + eloc);
        ((uint4*)(msg + (size_t)dr * HIDC))[wq] =
            make_uint4(w4[0], w4[1], w4[2], w4[3]);
    }
}

// Layer-2 messages via MFMA (32 -> 16), TWO chunks per wave, pedges linear
// read. 1 MFMA per 16-edge tile; word c of a row = half2{ch c, ch c+8} via
// the shfl_xor fold; in-wave transpose packs 32-B rows (lanes 2e,2e+1).
__global__ __launch_bounds__(256) void msg2_k(const __half* __restrict__ hh,
                                              const __half* __restrict__ W2f,
                                              const uint2* __restrict__ pedges,
                                              __half* __restrict__ msg) {
    int tid = threadIdx.x;
    int lane = tid & 63;
    int wv0 = (blockIdx.x * 256 + tid) >> 6;
    int waveA = wv0 << 1;
    if (waveA >= NCHUNK) return;
    bool hasB = (waveA + 1) < NCHUNK;
    int quad = lane >> 4, col = lane & 15;
    int isel2 = (lane >> 1) & 3;
    int e0 = (waveA << 6) + lane, e1 = e0 + 64;

    uint2 erA = pedges[e0];
    uint2 erB = hasB ? pedges[e1] : make_uint2(0u, 0x80000000u);
    int w1A = (int)erA.y, w1B = (int)erB.y;
    int relA = __builtin_amdgcn_readfirstlane((w1A >> 25) & 63);
    int relB = __builtin_amdgcn_readfirstlane((w1B >> 25) & 63);
    F16Bits fbA; fbA.u = (unsigned short)(erA.x >> 16);
    F16Bits fbB; fbB.u = (unsigned short)(erB.x >> 16);
    float scA = (float)fbA.f, scB = (float)fbB.f;
    int srcA = erA.x & 0xFFFF, srcB = erB.x & 0xFFFF;
    int drowA = (w1A < 0) ? NE : (w1A & 0x1FFFFFF);
    int drowB = (w1B < 0) ? NE : (w1B & 0x1FFFFFF);

    ABFrag bfA, bfB;
    bfA.u = ((const uint4*)W2f + (size_t)relA * 64)[lane];
    bfB.u = ((const uint4*)W2f + (size_t)relB * 64)[lane];
    ABFrag aA[4], aB[4];
    #pragma unroll
    for (int tl = 0; tl < 4; ++tl) {
        int sA = __shfl(srcA, tl * 16 + col);
        int sB = __shfl(srcB, tl * 16 + col);
        aA[tl].u = *((const uint4*)(hh + (size_t)sA * HIDC) + quad);
        aB[tl].u = *((const uint4*)(hh + (size_t)sB * HIDC) + quad);
    }
    #pragma unroll
    for (int tl = 0; tl < 4; ++tl) {
        f32x4 acc = {0.f, 0.f, 0.f, 0.f};
        acc = __builtin_amdgcn_mfma_f32_16x16x32_f16(aA[tl].f, bfA.f, acc, 0, 0, 0);
        unsigned um[4];
        #pragma unroll
        for (int i = 0; i < 4; ++i) {
            int ee = tl * 16 + quad * 4 + i;
            float si = __shfl(scA, ee);
            float vv = acc[i] * si;
            float p  = __shfl_xor(vv, 8);
            union { __half2 h; unsigned u; } cv;
            cv.h = __floats2half2_rn(vv, p);
            um[i] = cv.u;
        }
        unsigned w4[4];
        #pragma unroll
        for (int q = 0; q < 4; ++q) {
            int srcl = (((lane >> 3) << 4) + ((lane & 1) << 2) + q) & 63;
            unsigned t0 = __shfl(um[0], srcl);
            unsigned t1 = __shfl(um[1], srcl);
            unsigned t2 = __shfl(um[2], srcl);
            unsigned t3 = __shfl(um[3], srcl);
            w4[q] = (isel2 == 0) ? t0 : (isel2 == 1) ? t1 : (isel2 == 2) ? t2 : t3;
        }
        int dr = __shfl(drowA, (tl * 16 + (lane >> 1)) & 63);
        if (lane < 32) {
            ((uint4*)(msg + (size_t)dr * OUTC))[lane & 1] =
                make_uint4(w4[0], w4[1], w4[2], w4[3]);
        }
    }
    #pragma unroll
    for (int tl = 0; tl < 4; ++tl) {
        f32x4 acc = {0.f, 0.f, 0.f, 0.f};
        acc = __builtin_amdgcn_mfma_f32_16x16x32_f16(aB[tl].f, bfB.f, acc, 0, 0, 0);
        unsigned um[4];
        #pragma unroll
        for (int i = 0; i < 4; ++i) {
            int ee = tl * 16 + quad * 4 + i;
            float si = __shfl(scB, ee);
            float vv = acc[i] * si;
            float p  = __shfl_xor(vv, 8);
            union { __half2 h; unsigned u; } cv;
            cv.h = __floats2half2_rn(vv, p);
            um[i] = cv.u;
        }
        unsigned w4[4];
        #pragma unroll
        for (int q = 0; q < 4; ++q) {
            int srcl = (((lane >> 3) << 4) + ((lane & 1) << 2) + q) & 63;
            unsigned t0 = __shfl(um[0], srcl);
            unsigned t1 = __shfl(um[1], srcl);
            unsigned t2 = __shfl(um[2], srcl);
            unsigned t3 = __shfl(um[3], srcl);
            w4[q] = (isel2 == 0) ? t0 : (isel2 == 1) ? t1 : (isel2 == 2) ? t2 : t3;
        }
        int dr = __shfl(drowB, (tl * 16 + (lane >> 1)) & 63);
        if (lane < 32) {
            ((uint4*)(msg + (size_t)dr * OUTC))[lane & 1] =
                make_uint4(w4[0], w4[1], w4[2], w4[3]);
        }
    }
}

// ---------------------------------------------------------------------------
// Fused gather + node update 1: h = relu(sum(msg rows) + x @ root1 + b1), f16
// out. One wave per node. Lane (g = lane>>2, j = lane&3): loop k = k0+g step
// 16, uint4 load of row-quad j -> wave trip reads 16 contiguous rows (1 KB).
// Root term: in-channels 4g..4g+3 x out-words 4j..4j+3 with weights in
// REGISTERS from pre-permuted rootp1 (no LDS). Reduce over g via shfl_xor;
// lanes g==0 write the hh row as 4 coalesced uint4.
__global__ __launch_bounds__(256) void gather1_k(const __half* __restrict__ xh,
                                                 const float2* __restrict__ rootp1,
                                                 const float2* __restrict__ b1p,
                                                 const __half* __restrict__ msg,
                                                 const unsigned* __restrict__ rowptr,
                                                 __half* __restrict__ hh) {
    int tid = threadIdx.x;
    int lane = tid & 63;
    int wid = (blockIdx.x * 256 + tid) >> 6;   // node id; grid exact
    int g = lane >> 2, j = lane & 3;
    unsigned k0 = rowptr[wid], k1 = rowptr[wid + 1];
    // per-lane root weights: rw[i][q] = rootp1[(4g+i)*16 + 4j+q]
    float2 rw[4][4];
    #pragma unroll
    for (int i = 0; i < 4; ++i) {
        const float4* __restrict__ rp =
            (const float4*)rootp1 + ((4 * g + i) << 3) + 2 * j;
        float4 u0 = rp[0], u1 = rp[1];
        rw[i][0] = make_float2(u0.x, u0.y);
        rw[i][1] = make_float2(u0.z, u0.w);
        rw[i][2] = make_float2(u1.x, u1.y);
        rw[i][3] = make_float2(u1.z, u1.w);
    }
    float acc[8] = {0.f, 0.f, 0.f, 0.f, 0.f, 0.f, 0.f, 0.f};
    for (unsigned k = k0 + g; k < k1; k += 16) {
        uint4 v = ((const uint4*)(msg + (size_t)k * HIDC))[j];
        union { unsigned u; __half2 h; } c0, c1, c2, c3;
        c0.u = v.x; c1.u = v.y; c2.u = v.z; c3.u = v.w;
        float2 f0 = __half22float2(c0.h), f1 = __half22float2(c1.h);
        float2 f2 = __half22float2(c2.h), f3 = __half22float2(c3.h);
        acc[0] += f0.x; acc[1] += f0.y;
        acc[2] += f1.x; acc[3] += f1.y;
        acc[4] += f2.x; acc[5] += f2.y;
        acc[6] += f3.x; acc[7] += f3.y;
    }
    // root term: x channels 4g..4g+3
    union { uint2 u; __half2 h[2]; } xv;
    xv.u = ((const uint2*)(xh + (size_t)wid * INC))[g];
    float2 xa = __half22float2(xv.h[0]), xb = __half22float2(xv.h[1]);
    float xs[4] = { xa.x, xa.y, xb.x, xb.y };
    #pragma unroll
    for (int i = 0; i < 4; ++i) {
        #pragma unroll
        for (int q = 0; q < 4; ++q) {
            acc[2 * q]     = fmaf(xs[i], rw[i][q].x, acc[2 * q]);
            acc[2 * q + 1] = fmaf(xs[i], rw[i][q].y, acc[2 * q + 1]);
        }
    }
    #pragma unroll
    for (int off = 4; off < 64; off <<= 1) {
        #pragma unroll
        for (int q = 0; q < 8; ++q) acc[q] += __shfl_xor(acc[q], off);
    }
    if (g == 0) {
        const float4* __restrict__ bp4 = (const float4*)b1p;
        float4 bb0 = bp4[2 * j], bb1 = bp4[2 * j + 1];
        float2 bq[4] = { make_float2(bb0.x, bb0.y), make_float2(bb0.z, bb0.w),
                         make_float2(bb1.x, bb1.y), make_float2(bb1.z, bb1.w) };
        unsigned um[4];
        #pragma unroll
        for (int q = 0; q < 4; ++q) {
            float vx = acc[2 * q] + bq[q].x, vy = acc[2 * q + 1] + bq[q].y;
            union { __half2 h2; unsigned u; } cv;
            cv.h2 = __floats2half2_rn(vx > 0.f ? vx : 0.f, vy > 0.f ? vy : 0.f);
            um[q] = cv.u;
        }
        ((uint4*)(hh + (size_t)wid * HIDC))[j] = make_uint4(um[0], um[1], um[2], um[3]);
    }
}

// Fused gather + node update 2: out = sum(msg rows) + h @ root2 + b2 (f32 out).
// Lane (g = lane>>1, j = lane&1): loop k = k0+g step 32 (wave trip = 32 rows
// / 1 KB). Root: in-channel g (natural index; hh word (g&15) half (g>>4)),
// weights in registers from rootp2. Reduce over g; lanes g==0 write 2 float4.
__global__ __launch_bounds__(256) void gather2_k(const __half* __restrict__ hh,
                                                 const float2* __restrict__ rootp2,
                                                 const float* __restrict__ b2,
                                                 const __half* __restrict__ msg,
                                                 const unsigned* __restrict__ rowptr,
                                                 float* __restrict__ out) {
    int tid = threadIdx.x;
    int lane = tid & 63;
    int wid = (blockIdx.x * 256 + tid) >> 6;
    int g = lane >> 1, j = lane & 1;
    unsigned k0 = rowptr[wid], k1 = rowptr[wid + 1];
    // rw[q] = rootp2[g*8 + 4j+q] = {root2[g][4j+q], root2[g][4j+q+8]}
    const float4* __restrict__ rp = (const float4*)rootp2 + (g << 2) + 2 * j;
    float4 u0 = rp[0], u1 = rp[1];
    float2 rw[4] = { make_float2(u0.x, u0.y), make_float2(u0.z, u0.w),
                     make_float2(u1.x, u1.y), make_float2(u1.z, u1.w) };
    float acc[8] = {0.f, 0.f, 0.f, 0.f, 0.f, 0.f, 0.f, 0.f};
    for (unsigned k = k0 + g; k < k1; k += 32) {
        uint4 v = ((const uint4*)(msg + (size_t)k * OUTC))[j];
        union { unsigned u; __half2 h; } c0, c1, c2, c3;
        c0.u = v.x; c1.u = v.y; c2.u = v.z; c3.u = v.w;
        float2 f0 = __half22float2(c0.h), f1 = __half22float2(c1.h);
        float2 f2 = __half22float2(c2.h), f3 = __half22float2(c3.h);
        acc[0] += f0.x; acc[1] += f0.y;
        acc[2] += f1.x; acc[3] += f1.y;
        acc[4] += f2.x; acc[5] += f2.y;
        acc[6] += f3.x; acc[7] += f3.y;
    }
    // h channel g: hh word (g&15) = {ch g&15, ch (g&15)+16}
    unsigned hw = ((const unsigned*)(hh + (size_t)wid * HIDC))[g & 15];
    union { unsigned u; __half2 h; } hc; hc.u = hw;
    float2 hf = __half22float2(hc.h);
    float hv = (g < 16) ? hf.x : hf.y;
    #pragma unroll
    for (int q = 0; q < 4; ++q) {
        acc[2 * q]     = fmaf(hv, rw[q].x, acc[2 * q]);
        acc[2 * q + 1] = fmaf(hv, rw[q].y, acc[2 * q + 1]);
    }
    #pragma unroll
    for (int off = 2; off < 64; off <<= 1) {
        #pragma unroll
        for (int q = 0; q < 8; ++q) acc[q] += __shfl_xor(acc[q], off);
    }
    if (g == 0) {
        float* __restrict__ orow = out + (size_t)wid * OUTC;
        float4 ba = ((const float4*)b2)[j];        // channels 4j..4j+3
        float4 bb = ((const float4*)b2)[j + 2];    // channels 4j+8..4j+11
        ((float4*)orow)[j] = make_float4(acc[0] + ba.x, acc[2] + ba.y,
                                         acc[4] + ba.z, acc[6] + ba.w);
        ((float4*)orow)[j + 2] = make_float4(acc[1] + bb.x, acc[3] + bb.y,
                                             acc[5] + bb.z, acc[7] + bb.w);
    }
}

// ---------------------------------------------------------------------------
extern "C" void kernel_launch(void* const* d_in, const int* in_sizes, int n_in,
                              void* d_out, int out_size, void* d_ws, size_t ws_size,
                              hipStream_t stream) {
    const float* x     = (const float*)d_in[0];
    const int*   ei    = (const int*)d_in[1];   // [2, NE]
    const int*   et    = (const int*)d_in[2];   // [NE]
    const float* W1    = (const float*)d_in[3];
    const float* root1 = (const float*)d_in[4];
    const float* b1    = (const float*)d_in[5];
    const float* W2    = (const float*)d_in[6];
    const float* root2 = (const float*)d_in[7];
    const float* b2    = (const float*)d_in[8];
    float* out = (float*)d_out;

    char* ws = (char*)d_ws;
    size_t o = 0;
    auto alloc = [&](size_t bytes) -> char* {
        char* p = ws + o;
        o = (o + bytes + 255) & ~(size_t)255;
        return p;
    };
    // Everything initialized inside the kernels (rsorted pad init + flag
    // zeroing live in preph_k). No memset node.
    unsigned* rsorted = (unsigned*)alloc((size_t)MAXE * 4);        // 4.8 MB
    unsigned* flagbuf = (unsigned*)alloc(256 * 4);    // [32..227]=dp flags
    unsigned* ghist   = (unsigned*)alloc((size_t)NR * NB * 4);     // [rel][NB]
    unsigned* rngs    = (unsigned*)alloc((size_t)NR * 2 * 4);
    int*      chunkrel= (int*)     alloc((size_t)NCHUNK * 4);
    unsigned short* rank16 = (unsigned short*)alloc((size_t)MAXE * 2);
    unsigned short* cnt16  = (unsigned short*)alloc((size_t)NR * NN * 2); // 4.5 MB
    unsigned* packed  = (unsigned*)alloc((size_t)NR * NN * 4);     // 9.0 MB
    unsigned* rowptr  = (unsigned*)alloc(((size_t)NN + 1) * 4);
    uint2*    pedges  = (uint2*)   alloc((size_t)MAXE * 8);        // 9.6 MB
    __half*   W1f     = (__half*)  alloc((size_t)NR * 2048 * 2);
    __half*   W2f     = (__half*)  alloc((size_t)NR * 512 * 2);
    __half*   xh      = (__half*)  alloc((size_t)NN * INC * 2);    // 6.4 MB
    __half*   hh      = (__half*)  alloc((size_t)NN * HIDC * 2);   // 3.2 MB
    float2*   rootp1  = (float2*)  alloc(1024 * 8);                // 8 KB
    float2*   rootp2  = (float2*)  alloc(256 * 8);                 // 2 KB
    float2*   b1p     = (float2*)  alloc(16 * 8);
    // msg buffers alias: msg1 (f16, 64-B rows) fully consumed by gather1
    // before msg2 (f16, 32-B rows) is produced.
    char*     msgraw  = alloc(((size_t)NE + 1) * 64);              // 76.9 MB
    __half*   msg1    = (__half*)msgraw;
    __half*   msg2    = (__half*)msgraw;

    int prep_grid = NN * INC / 2 / 256;   // 6250 >= NB, covers all prep work
    int msg_grid = (NCHUNK + 7) / 8;      // 4 waves/block x 2 chunks/wave
    preph_k   <<<prep_grid, 256, 0, stream>>>(W1, W2, x, ei, et, root1, root2, b1,
                                              W1f, W2f, xh, rootp1, rootp2, b1p,
                                              ghist, rsorted, flagbuf);
    scat_k    <<<NB, 1024, 0, stream>>>(ei, et, ghist, rngs, chunkrel, rsorted);
    relcnt_k  <<<4 * NR, 1024, 0, stream>>>(rsorted, rngs, cnt16, rank16);
    dp_k      <<<NTILE, 256, 0, stream>>>(cnt16, packed, rowptr, flagbuf + 32);
    msg1_k    <<<msg_grid, 256, 0, stream>>>(xh, W1f, rsorted, rank16,
                                             packed, rowptr, chunkrel,
                                             pedges, msg1);
    gather1_k <<<NN * 64 / 256, 256, 0, stream>>>(xh, rootp1, b1p, msg1, rowptr, hh);
    msg2_k    <<<msg_grid, 256, 0, stream>>>(hh, W2f, pedges, msg2);
    gather2_k <<<NN * 64 / 256, 256, 0, stream>>>(hh, rootp2, b2, msg2, rowptr, out);
}

// Round 10
// 286.757 us; speedup vs baseline: 1.0830x; 1.0259x over previous
//
#include <hip/hip_runtime.h>
#include <hip/hip_fp16.h>
#include <cstdint>
#include <cstddef>

// Problem constants (match reference setup_inputs)
#define NN   50000      // nodes  (< 65536: src/dst fit 16 bits)
#define NE   1200000    // edges
#define NR   45         // relations
#define INC  64
#define HIDC 32
#define OUTC 16
// Padded edge capacity: each relation bucket padded to multiple of 64 so every
// wave's 64 edges share one relation. NE + NR*64, itself a multiple of 64.
#define MAXE 1202880
#define NCHUNK (MAXE/64)
// relation counting-sort blocking
#define EPB 4096
#define NB  ((NE + EPB - 1) / EPB)      // 293 blocks
// relcnt: 4 dst-quarters per relation; 6250 LDS words x two u16 = 12500 dsts
#define QDW 6250
#define QDD 12500                       // 4*12500 = 50000 = NN exactly
// dp_k lookback tiles (256 dsts each)
#define NTILE ((NN + 255) / 256)        // 196

// Message rows are stored CHANNEL-INTERLEAVED (no LDS transpose needed):
//   layer-1 row word c (c=0..15) = half2{ ch c, ch c+16 }
//   layer-2 row word c (c=0..7)  = half2{ ch c, ch c+8  }
// hh is stored with the layer-1 interleave: stored element s <-> channel
// (s>>1) + (s&1)*16. W2f bakes the inverse permutation into its k index.
// Gathers read msg rows 16 B/lane and keep root weights in REGISTERS.
// finalize is FUSED into msg1 (builds records inline, writes pedges as a
// side product); msg2 reads pedges linearly.
// msg stores go through an IN-WAVE shfl transpose (whole 64-B rows/instr).
// EXPERIMENT LOG (all falsified, do not retry):
//  R2: nontemporal loads/stores -> big regression (defeats L2 write-merge).
//  R5+R8: (src-group, rel) bucketing for gather locality -> FETCH unchanged.
//  R7: store-segment coalescing (this transpose) -> neutral (kept: harmless).
//  R8: dropping pedges / re-deriving in msg2 -> regression (2x packed gather).
//  R9: 2-chunk-per-wave ILP -> regression (VGPR 36->64, occupancy 56->30%;
//      latency-bound msg1 needs TLP more than intra-wave ILP).
// Conclusion: msg1 ~46us is a scatter-gather latency floor for this
// decomposition; pipeline is at its practical roofline (~292 us).

typedef _Float16 f16x8 __attribute__((ext_vector_type(8)));
typedef float    f32x4 __attribute__((ext_vector_type(4)));

union F16Bits { unsigned short u; _Float16 f; };
union ABFrag   { uint4 u; f16x8 f; };

// ---------------------------------------------------------------------------
// Fused prep + relation histogram + buffer init. All blocks do striped prep
// work (MFMA B-fragments in exact lane order + x f32->f16 cast + rsorted pad
// init + dp-flag zeroing + permuted root/bias tables for the gathers); the
// first NB blocks also build the per-block 45-bin relation histogram
// (4 per-wave LDS sub-histograms). ghist layout is TRANSPOSED: [rel][NB].
//   B[k][n] fragment for 16x16x32: lane holds k=(lane>>4)*8+j, n=lane&15.
__global__ __launch_bounds__(256) void preph_k(const float* __restrict__ W1,
                                               const float* __restrict__ W2,
                                               const float* __restrict__ x,
                                               const int* __restrict__ ei,
                                               const int* __restrict__ et,
                                               const float* __restrict__ root1,
                                               const float* __restrict__ root2,
                                               const float* __restrict__ b1,
                                               __half* __restrict__ W1f,
                                               __half* __restrict__ W2f,
                                               __half* __restrict__ xh,
                                               float2* __restrict__ rootp1,
                                               float2* __restrict__ rootp2,
                                               float2* __restrict__ b1p,
                                               unsigned* __restrict__ ghist,
                                               unsigned* __restrict__ rsorted,
                                               unsigned* __restrict__ flagbuf) {
    __shared__ unsigned lh[4 * 48];   // 4 per-wave sub-histograms (48: bank pad)
    int t = threadIdx.x, b = blockIdx.x;
    int wv = t >> 6;
    if (t < 192) lh[t] = 0;
    __syncthreads();
    if (b < NB) {
        #pragma unroll
        for (int it = 0; it < EPB / 256; ++it) {
            int e = b * EPB + it * 256 + t;
            if (e < NE) {
                int r = et[e], src = ei[e], dst = ei[NE + e];
                if ((unsigned)r < NR && (unsigned)src < NN && (unsigned)dst < NN)
                    atomicAdd(&lh[wv * 48 + r], 1u);
            }
        }
    }
    __syncthreads();
    if (b < NB && t < NR)
        ghist[t * NB + b] = lh[t] + lh[48 + t] + lh[96 + t] + lh[144 + t];
    int g = b * 256 + t;
    int gthreads = gridDim.x * 256;
    // pad-sentinel init (replaces hipMemsetAsync node)
    for (int i = g; i < MAXE; i += gthreads) rsorted[i] = 0xFFFFFFFFu;
    if (b == 0) flagbuf[t] = 0;     // words 32..227: dp lookback flags
    if (g < NR * 2048) {
        int r = g >> 11, rem = g & 2047;
        int kb = rem >> 10, nb = (rem >> 9) & 1;
        int lane = (rem >> 3) & 63, j = rem & 7;
        int k = kb * 32 + (lane >> 4) * 8 + j;
        int n = nb * 16 + (lane & 15);
        W1f[g] = __float2half(W1[(r * INC + k) * HIDC + n]);
    }
    if (g < NR * 512) {
        int r = g >> 9, rem = g & 511;
        int lane = (rem >> 3) & 63, j = rem & 7;
        int k = (lane >> 4) * 8 + j;          // stored k index s
        int kc = (k >> 1) + ((k & 1) << 4);   // channel = perm(s) to match hh
        int n = lane & 15;
        W2f[g] = __float2half(W2[(r * HIDC + kc) * OUTC + n]);
    }
    if (g < NN * INC / 2) {
        float2 f = ((const float2*)x)[g];
        union { __half2 h; unsigned u; } cv;
        cv.h = __floats2half2_rn(f.x, f.y);
        ((unsigned*)xh)[g] = cv.u;
    }
    // permuted gather tables: rootp1[in*16+w] = {root1[in][w], root1[in][w+16]}
    if (g < 1024) {
        int in = g >> 4, w = g & 15;
        rootp1[g] = make_float2(root1[in * HIDC + w], root1[in * HIDC + w + 16]);
    }
    if (g < 256) {
        int in = g >> 3, w = g & 7;
        rootp2[g] = make_float2(root2[in * OUTC + w], root2[in * OUTC + w + 8]);
    }
    if (g < 16) b1p[g] = make_float2(b1[g], b1[g + 16]);
}

// ---------------------------------------------------------------------------
// Scatter into relation buckets — NO serial scan phase, NO spin. Each block
// derives its own deterministic base from the L2-resident per-relation
// histogram row: lbase[r] = relbase[r] + sum_{b<bx} ghist[r][b] (45 lanes
// stream NB sequential words each). Block 0 additionally writes rngs +
// chunkrel (consumed only by later dispatches). Pads keep the sentinel.
__global__ __launch_bounds__(1024) void scat_k(const int* __restrict__ ei,
                                               const int* __restrict__ et,
                                               const unsigned* __restrict__ ghist,
                                               unsigned* __restrict__ rngs,
                                               int* __restrict__ chunkrel,
                                               unsigned* __restrict__ rsorted) {
    __shared__ unsigned reltot[NR];       // column totals
    __shared__ unsigned mypart[NR];       // partial prefix up to this block
    __shared__ unsigned relbase[NR + 1];  // padded bucket bases
    __shared__ unsigned lbase[NR], lcur[NR];
    int t = threadIdx.x, bx = blockIdx.x;
    if (t < NR) {
        unsigned total = 0, part = 0;
        const unsigned* __restrict__ row = ghist + t * NB;
        for (int b = 0; b < NB; ++b) {
            if (b == bx) part = total;
            total += row[b];
        }
        reltot[t] = total;
        mypart[t] = part;
        lcur[t] = 0;
    }
    __syncthreads();
    if (t == 0) {
        unsigned acc = 0;
        for (int r = 0; r < NR; ++r) {
            relbase[r] = acc;
            acc += ((reltot[r] + 63u) >> 6) << 6;
        }
        relbase[NR] = acc;
    }
    __syncthreads();
    if (t < NR) lbase[t] = relbase[t] + mypart[t];
    __syncthreads();
    #pragma unroll
    for (int it = 0; it < EPB / 1024; ++it) {
        int e = bx * EPB + it * 1024 + t;
        if (e < NE) {
            int r = et[e], src = ei[e], dst = ei[NE + e];
            if ((unsigned)r < NR && (unsigned)src < NN && (unsigned)dst < NN) {
                unsigned local = atomicAdd(&lcur[r], 1u);
                rsorted[lbase[r] + local] = (unsigned)src | ((unsigned)dst << 16);
            }
        }
    }
    if (bx == 0) {
        if (t < NR) {
            rngs[2 * t]     = relbase[t];
            rngs[2 * t + 1] = relbase[t] + reltot[t];
        }
        for (int c = t; c < NCHUNK; c += 1024) {
            unsigned pos = (unsigned)c << 6;
            int lo = 0, hi = NR - 1;
            while (lo < hi) {
                int mid = (lo + hi + 1) >> 1;
                if (relbase[mid] <= pos) lo = mid; else hi = mid - 1;
            }
            chunkrel[c] = lo;
        }
    }
}

// Per-relation dst counts + per-edge rank in ONE pass (the atomic's old value
// is the rank; the final LDS word is the count). Four dst-quarters per
// relation (25 KB LDS) -> 180 blocks; the 4 co-scans of a bucket share L2.
__global__ __launch_bounds__(1024) void relcnt_k(const unsigned* __restrict__ rsorted,
                                                 const unsigned* __restrict__ rngs,
                                                 unsigned short* __restrict__ cnt16,
                                                 unsigned short* __restrict__ rank16) {
    __shared__ unsigned lds[QDW];     // 25000 B
    int r = blockIdx.x >> 2, q = blockIdx.x & 3, t = threadIdx.x;
    unsigned base = rngs[2 * r], end = rngs[2 * r + 1];
    unsigned dlo = q * QDD, dhi = dlo + QDD;   // 4*12500 = NN exactly
    for (int w = t; w < QDW; w += 1024) lds[w] = 0;
    __syncthreads();
    for (unsigned s = base + t; s < end; s += 1024) {
        unsigned d = rsorted[s] >> 16;
        if (d >= dlo && d < dhi) {
            unsigned off = d - dlo;
            unsigned old = atomicAdd(&lds[off >> 1], (off & 1) ? 0x10000u : 1u);
            rank16[s] = (unsigned short)((off & 1) ? (old >> 16) : (old & 0xFFFFu));
        }
    }
    __syncthreads();
    unsigned* __restrict__ cp = (unsigned*)(cnt16 + (size_t)r * NN + dlo);
    for (int w = t; w < QDW; w += 1024) cp[w] = lds[w];
}

// ---------------------------------------------------------------------------
// Fused drel + dprefix via decoupled lookback. Tile = 256 dsts. Per dst:
// relation-prefix offsets + f16 inverse counts packed into one word per
// (r,dst); block-scan of degrees; lookback chain carries block sums INSIDE
// the atomic flag word {state:2 | sum:30} -> no non-atomic cross-block data.
__global__ __launch_bounds__(256) void dp_k(const unsigned short* __restrict__ cnt16,
                                            unsigned* __restrict__ packed,
                                            unsigned* __restrict__ rowptr,
                                            unsigned* __restrict__ flags) {
    __shared__ unsigned wsum[4];
    __shared__ unsigned excl_s;
    int t = threadIdx.x, b = blockIdx.x;
    int lane = t & 63, wv = t >> 6;
    int dst = b * 256 + t;
    unsigned deg = 0;
    if (dst < NN) {
        unsigned run = 0;
        #pragma unroll 5
        for (int r = 0; r < NR; ++r) {
            unsigned c = cnt16[(size_t)r * NN + dst];
            F16Bits fb; fb.f = (_Float16)(c ? 1.0f / (float)c : 0.0f);
            packed[(size_t)r * NN + dst] = (run & 0xFFFFu) | ((unsigned)fb.u << 16);
            run += c;
        }
        deg = run;
    }
    unsigned s = deg;                      // inclusive wave scan
    #pragma unroll
    for (int off = 1; off < 64; off <<= 1) {
        unsigned n = __shfl_up(s, off);
        if (lane >= off) s += n;
    }
    if (lane == 63) wsum[wv] = s;
    __syncthreads();
    unsigned waveoff = 0;
    if (wv > 0) waveoff += wsum[0];
    if (wv > 1) waveoff += wsum[1];
    if (wv > 2) waveoff += wsum[2];
    unsigned blockT = wsum[0] + wsum[1] + wsum[2] + wsum[3];
    unsigned local_excl = waveoff + s - deg;
    if (t == 0) {
        if (b == 0) {
            excl_s = 0;
            atomicExch(&flags[0], 0x80000000u | blockT);     // state 2 (inclusive)
        } else {
            atomicExch(&flags[b], 0x40000000u | blockT);     // state 1 (aggregate)
            unsigned ex = 0;
            int p = b - 1;
            while (p >= 0) {
                unsigned f = atomicAdd(&flags[p], 0u);
                unsigned st = f >> 30;
                if (st == 0) continue;                        // spin
                ex += f & 0x3FFFFFFFu;
                if (st >= 2) break;
                --p;
            }
            excl_s = ex;
            atomicExch(&flags[b], 0x80000000u | (ex + blockT));
        }
    }
    __syncthreads();
    unsigned ex = excl_s;
    if (dst < NN) rowptr[dst] = ex + local_excl;
    if (b == (int)gridDim.x - 1 && t == 0) rowptr[NN] = ex + blockT;
}

// ---------------------------------------------------------------------------
// Layer-1 messages via MFMA, with finalize FUSED into the prologue. One wave
// = 64 edges of ONE relation = 4 tiles of 16 edges; 4x mfma per tile. The
// per-edge record (src, scale, dpos) is built inline from rsorted/rank16/
// packed/rowptr/chunkrel, and pedges is written as a side product so msg2
// keeps a cheap linear read. The MFMA C layout (edge = quad*4+i, channel =
// col/col+16) is transposed IN-WAVE (16 shfls/tile) so each store instr
// writes 16 full 64-B rows (16 segments) instead of 64 scattered dwords.
__global__ __launch_bounds__(256) void msg1_k(const __half* __restrict__ xh,
                                              const __half* __restrict__ W1f,
                                              const unsigned* __restrict__ rsorted,
                                              const unsigned short* __restrict__ rank16,
                                              const unsigned* __restrict__ packed,
                                              const unsigned* __restrict__ rowptr,
                                              const int* __restrict__ chunkrel,
                                              uint2* __restrict__ pedges,
                                              __half* __restrict__ msg) {
    int tid = threadIdx.x;
    int lane = tid & 63;
    int wave = (blockIdx.x * 256 + tid) >> 6;
    if (wave >= NCHUNK) return;
    int e = (wave << 6) + lane;
    int rel = __builtin_amdgcn_readfirstlane(chunkrel[wave]);   // wave-uniform
    unsigned v = rsorted[e];
    unsigned dst = v >> 16;
    int src = 0, drow = NE;
    float sc = 0.f;
    uint2 pe = make_uint2(0u, 0x80000000u);
    if (dst < NN) {
        unsigned pk = packed[(size_t)rel * NN + dst];
        unsigned dpos = rowptr[dst] + (pk & 0xFFFFu) + (unsigned)rank16[e];
        src = v & 0xFFFF;
        F16Bits fb; fb.u = (unsigned short)(pk >> 16);
        sc = (float)fb.f;
        drow = (int)dpos;
        pe = make_uint2((v & 0xFFFFu) | (pk & 0xFFFF0000u),
                        dpos | ((unsigned)rel << 25));
    }
    pedges[e] = pe;
    const uint4* __restrict__ wf = (const uint4*)W1f + (size_t)rel * 256;
    ABFrag b00, b01, b10, b11;
    b00.u = wf[0 * 64 + lane];
    b01.u = wf[1 * 64 + lane];
    b10.u = wf[2 * 64 + lane];
    b11.u = wf[3 * 64 + lane];
    int quad = lane >> 4, col = lane & 15;
    ABFrag a0[4], a1[4];
    #pragma unroll
    for (int tl = 0; tl < 4; ++tl) {
        int s = __shfl(src, tl * 16 + col);
        const uint4* __restrict__ xp = (const uint4*)(xh + (size_t)s * INC) + quad;
        a0[tl].u = xp[0];
        a1[tl].u = xp[4];
    }
    int eloc = lane >> 2, wq = lane & 3, isel = eloc & 3;
    #pragma unroll
    for (int tl = 0; tl < 4; ++tl) {
        f32x4 acc0 = {0.f, 0.f, 0.f, 0.f}, acc1 = {0.f, 0.f, 0.f, 0.f};
        acc0 = __builtin_amdgcn_mfma_f32_16x16x32_f16(a0[tl].f, b00.f, acc0, 0, 0, 0);
        acc0 = __builtin_amdgcn_mfma_f32_16x16x32_f16(a1[tl].f, b10.f, acc0, 0, 0, 0);
        acc1 = __builtin_amdgcn_mfma_f32_16x16x32_f16(a0[tl].f, b01.f, acc1, 0, 0, 0);
        acc1 = __builtin_amdgcn_mfma_f32_16x16x32_f16(a1[tl].f, b11.f, acc1, 0, 0, 0);
        unsigned um[4];
        #pragma unroll
        for (int i = 0; i < 4; ++i) {
            int ee = tl * 16 + quad * 4 + i;          // edge owning this D row
            float si = __shfl(sc, ee);
            union { __half2 h; unsigned u; } cv;
            cv.h = __floats2half2_rn(acc0[i] * si, acc1[i] * si);
            um[i] = cv.u;                             // word col of edge ee
        }
        // in-wave 16x16 dword transpose: lane (eloc,wq) gathers words
        // 4wq..4wq+3 of edge tl*16+eloc from lanes (eloc>>2)*16 + w.
        unsigned w4[4];
        #pragma unroll
        for (int q = 0; q < 4; ++q) {
            int srcl = ((lane >> 4) << 4) + (wq << 2) + q;
            unsigned t0 = __shfl(um[0], srcl);
            unsigned t1 = __shfl(um[1], srcl);
            unsigned t2 = __shfl(um[2], srcl);
            unsigned t3 = __shfl(um[3], srcl);
            w4[q] = (isel == 0) ? t0 : (isel == 1) ? t1 : (isel == 2) ? t2 : t3;
        }
        int dr = __shfl(drow, tl * 16 + eloc);
        ((uint4*)(msg + (size_t)dr * HIDC))[wq] =
            make_uint4(w4[0], w4[1], w4[2], w4[3]);
    }
}

// Layer-2 messages via MFMA (32 -> 16): 1 MFMA per 16-edge tile. Word c of a
// row = half2{ch c, ch c+8} built by the shfl_xor fold; then the same in-wave
// transpose packs rows into uint4s: lanes 2e,2e+1 store the 32-B row of edge
// e (16 segments/instr instead of 128 scattered dwords).
__global__ __launch_bounds__(256) void msg2_k(const __half* __restrict__ hh,
                                              const __half* __restrict__ W2f,
                                              const uint2* __restrict__ pedges,
                                              __half* __restrict__ msg) {
    int tid = threadIdx.x;
    int lane = tid & 63;
    int wave = (blockIdx.x * 256 + tid) >> 6;
    if (wave >= NCHUNK) return;
    int e = (wave << 6) + lane;
    uint2 er = pedges[e];
    int w1 = (int)er.y;
    int rel = __builtin_amdgcn_readfirstlane((w1 >> 25) & 63);
    F16Bits fb; fb.u = (unsigned short)(er.x >> 16);
    float sc = (float)fb.f;
    int src = er.x & 0xFFFF;
    int drow = (w1 < 0) ? NE : (w1 & 0x1FFFFFF);
    ABFrag bf;
    bf.u = ((const uint4*)W2f + (size_t)rel * 64)[lane];
    int quad = lane >> 4, col = lane & 15;
    ABFrag a[4];
    #pragma unroll
    for (int tl = 0; tl < 4; ++tl) {
        int s = __shfl(src, tl * 16 + col);
        a[tl].u = *((const uint4*)(hh + (size_t)s * HIDC) + quad);
    }
    int isel2 = (lane >> 1) & 3;
    #pragma unroll
    for (int tl = 0; tl < 4; ++tl) {
        f32x4 acc = {0.f, 0.f, 0.f, 0.f};
        acc = __builtin_amdgcn_mfma_f32_16x16x32_f16(a[tl].f, bf.f, acc, 0, 0, 0);
        unsigned um[4];
        #pragma unroll
        for (int i = 0; i < 4; ++i) {
            int ee = tl * 16 + quad * 4 + i;
            float si = __shfl(sc, ee);
            float vv = acc[i] * si;
            float p  = __shfl_xor(vv, 8);            // partner channel col^8
            union { __half2 h; unsigned u; } cv;
            cv.h = __floats2half2_rn(vv, p);         // {ch col, ch col+8}
            um[i] = cv.u;                            // valid on lanes col<8
        }
        // transpose: lane (e2=lane>>1, wq2=lane&1) gathers words 4wq2..4wq2+3
        // of edge tl*16+e2 from lanes (e2>>2)*16 + w (w<8 -> col<8 sources).
        unsigned w4[4];
        #pragma unroll
        for (int q = 0; q < 4; ++q) {
            int srcl = (((lane >> 3) << 4) + ((lane & 1) << 2) + q) & 63;
            unsigned t0 = __shfl(um[0], srcl);
            unsigned t1 = __shfl(um[1], srcl);
            unsigned t2 = __shfl(um[2], srcl);
            unsigned t3 = __shfl(um[3], srcl);
            w4[q] = (isel2 == 0) ? t0 : (isel2 == 1) ? t1 : (isel2 == 2) ? t2 : t3;
        }
        int dr = __shfl(drow, (tl * 16 + (lane >> 1)) & 63);
        if (lane < 32) {
            ((uint4*)(msg + (size_t)dr * OUTC))[lane & 1] =
                make_uint4(w4[0], w4[1], w4[2], w4[3]);
        }
    }
}

// ---------------------------------------------------------------------------
// Fused gather + node update 1: h = relu(sum(msg rows) + x @ root1 + b1), f16
// out. One wave per node. Lane (g = lane>>2, j = lane&3): loop k = k0+g step
// 16, uint4 load of row-quad j -> wave trip reads 16 contiguous rows (1 KB).
// Root term: in-channels 4g..4g+3 x out-words 4j..4j+3 with weights in
// REGISTERS from pre-permuted rootp1 (no LDS). Reduce over g via shfl_xor;
// lanes g==0 write the hh row as 4 coalesced uint4.
__global__ __launch_bounds__(256) void gather1_k(const __half* __restrict__ xh,
                                                 const float2* __restrict__ rootp1,
                                                 const float2* __restrict__ b1p,
                                                 const __half* __restrict__ msg,
                                                 const unsigned* __restrict__ rowptr,
                                                 __half* __restrict__ hh) {
    int tid = threadIdx.x;
    int lane = tid & 63;
    int wid = (blockIdx.x * 256 + tid) >> 6;   // node id; grid exact
    int g = lane >> 2, j = lane & 3;
    unsigned k0 = rowptr[wid], k1 = rowptr[wid + 1];
    // per-lane root weights: rw[i][q] = rootp1[(4g+i)*16 + 4j+q]
    float2 rw[4][4];
    #pragma unroll
    for (int i = 0; i < 4; ++i) {
        const float4* __restrict__ rp =
            (const float4*)rootp1 + ((4 * g + i) << 3) + 2 * j;
        float4 u0 = rp[0], u1 = rp[1];
        rw[i][0] = make_float2(u0.x, u0.y);
        rw[i][1] = make_float2(u0.z, u0.w);
        rw[i][2] = make_float2(u1.x, u1.y);
        rw[i][3] = make_float2(u1.z, u1.w);
    }
    float acc[8] = {0.f, 0.f, 0.f, 0.f, 0.f, 0.f, 0.f, 0.f};
    for (unsigned k = k0 + g; k < k1; k += 16) {
        uint4 v = ((const uint4*)(msg + (size_t)k * HIDC))[j];
        union { unsigned u; __half2 h; } c0, c1, c2, c3;
        c0.u = v.x; c1.u = v.y; c2.u = v.z; c3.u = v.w;
        float2 f0 = __half22float2(c0.h), f1 = __half22float2(c1.h);
        float2 f2 = __half22float2(c2.h), f3 = __half22float2(c3.h);
        acc[0] += f0.x; acc[1] += f0.y;
        acc[2] += f1.x; acc[3] += f1.y;
        acc[4] += f2.x; acc[5] += f2.y;
        acc[6] += f3.x; acc[7] += f3.y;
    }
    // root term: x channels 4g..4g+3
    union { uint2 u; __half2 h[2]; } xv;
    xv.u = ((const uint2*)(xh + (size_t)wid * INC))[g];
    float2 xa = __half22float2(xv.h[0]), xb = __half22float2(xv.h[1]);
    float xs[4] = { xa.x, xa.y, xb.x, xb.y };
    #pragma unroll
    for (int i = 0; i < 4; ++i) {
        #pragma unroll
        for (int q = 0; q < 4; ++q) {
            acc[2 * q]     = fmaf(xs[i], rw[i][q].x, acc[2 * q]);
            acc[2 * q + 1] = fmaf(xs[i], rw[i][q].y, acc[2 * q + 1]);
        }
    }
    #pragma unroll
    for (int off = 4; off < 64; off <<= 1) {
        #pragma unroll
        for (int q = 0; q < 8; ++q) acc[q] += __shfl_xor(acc[q], off);
    }
    if (g == 0) {
        const float4* __restrict__ bp4 = (const float4*)b1p;
        float4 bb0 = bp4[2 * j], bb1 = bp4[2 * j + 1];
        float2 bq[4] = { make_float2(bb0.x, bb0.y), make_float2(bb0.z, bb0.w),
                         make_float2(bb1.x, bb1.y), make_float2(bb1.z, bb1.w) };
        unsigned um[4];
        #pragma unroll
        for (int q = 0; q < 4; ++q) {
            float vx = acc[2 * q] + bq[q].x, vy = acc[2 * q + 1] + bq[q].y;
            union { __half2 h2; unsigned u; } cv;
            cv.h2 = __floats2half2_rn(vx > 0.f ? vx : 0.f, vy > 0.f ? vy : 0.f);
            um[q] = cv.u;
        }
        ((uint4*)(hh + (size_t)wid * HIDC))[j] = make_uint4(um[0], um[1], um[2], um[3]);
    }
}

// Fused gather + node update 2: out = sum(msg rows) + h @ root2 + b2 (f32 out).
// Lane (g = lane>>1, j = lane&1): loop k = k0+g step 32 (wave trip = 32 rows
// / 1 KB). Root: in-channel g (natural index; hh word (g&15) half (g>>4)),
// weights in registers from rootp2. Reduce over g; lanes g==0 write 2 float4.
__global__ __launch_bounds__(256) void gather2_k(const __half* __restrict__ hh,
                                                 const float2* __restrict__ rootp2,
                                                 const float* __restrict__ b2,
                                                 const __half* __restrict__ msg,
                                                 const unsigned* __restrict__ rowptr,
                                                 float* __restrict__ out) {
    int tid = threadIdx.x;
    int lane = tid & 63;
    int wid = (blockIdx.x * 256 + tid) >> 6;
    int g = lane >> 1, j = lane & 1;
    unsigned k0 = rowptr[wid], k1 = rowptr[wid + 1];
    // rw[q] = rootp2[g*8 + 4j+q] = {root2[g][4j+q], root2[g][4j+q+8]}
    const float4* __restrict__ rp = (const float4*)rootp2 + (g << 2) + 2 * j;
    float4 u0 = rp[0], u1 = rp[1];
    float2 rw[4] = { make_float2(u0.x, u0.y), make_float2(u0.z, u0.w),
                     make_float2(u1.x, u1.y), make_float2(u1.z, u1.w) };
    float acc[8] = {0.f, 0.f, 0.f, 0.f, 0.f, 0.f, 0.f, 0.f};
    for (unsigned k = k0 + g; k < k1; k += 32) {
        uint4 v = ((const uint4*)(msg + (size_t)k * OUTC))[j];
        union { unsigned u; __half2 h; } c0, c1, c2, c3;
        c0.u = v.x; c1.u = v.y; c2.u = v.z; c3.u = v.w;
        float2 f0 = __half22float2(c0.h), f1 = __half22float2(c1.h);
        float2 f2 = __half22float2(c2.h), f3 = __half22float2(c3.h);
        acc[0] += f0.x; acc[1] += f0.y;
        acc[2] += f1.x; acc[3] += f1.y;
        acc[4] += f2.x; acc[5] += f2.y;
        acc[6] += f3.x; acc[7] += f3.y;
    }
    // h channel g: hh word (g&15) = {ch g&15, ch (g&15)+16}
    unsigned hw = ((const unsigned*)(hh + (size_t)wid * HIDC))[g & 15];
    union { unsigned u; __half2 h; } hc; hc.u = hw;
    float2 hf = __half22float2(hc.h);
    float hv = (g < 16) ? hf.x : hf.y;
    #pragma unroll
    for (int q = 0; q < 4; ++q) {
        acc[2 * q]     = fmaf(hv, rw[q].x, acc[2 * q]);
        acc[2 * q + 1] = fmaf(hv, rw[q].y, acc[2 * q + 1]);
    }
    #pragma unroll
    for (int off = 2; off < 64; off <<= 1) {
        #pragma unroll
        for (int q = 0; q < 8; ++q) acc[q] += __shfl_xor(acc[q], off);
    }
    if (g == 0) {
        float* __restrict__ orow = out + (size_t)wid * OUTC;
        float4 ba = ((const float4*)b2)[j];        // channels 4j..4j+3
        float4 bb = ((const float4*)b2)[j + 2];    // channels 4j+8..4j+11
        ((float4*)orow)[j] = make_float4(acc[0] + ba.x, acc[2] + ba.y,
                                         acc[4] + ba.z, acc[6] + ba.w);
        ((float4*)orow)[j + 2] = make_float4(acc[1] + bb.x, acc[3] + bb.y,
                                             acc[5] + bb.z, acc[7] + bb.w);
    }
}

// ---------------------------------------------------------------------------
extern "C" void kernel_launch(void* const* d_in, const int* in_sizes, int n_in,
                              void* d_out, int out_size, void* d_ws, size_t ws_size,
                              hipStream_t stream) {
    const float* x     = (const float*)d_in[0];
    const int*   ei    = (const int*)d_in[1];   // [2, NE]
    const int*   et    = (const int*)d_in[2];   // [NE]
    const float* W1    = (const float*)d_in[3];
    const float* root1 = (const float*)d_in[4];
    const float* b1    = (const float*)d_in[5];
    const float* W2    = (const float*)d_in[6];
    const float* root2 = (const float*)d_in[7];
    const float* b2    = (const float*)d_in[8];
    float* out = (float*)d_out;

    char* ws = (char*)d_ws;
    size_t o = 0;
    auto alloc = [&](size_t bytes) -> char* {
        char* p = ws + o;
        o = (o + bytes + 255) & ~(size_t)255;
        return p;
    };
    // Everything initialized inside the kernels (rsorted pad init + flag
    // zeroing live in preph_k). No memset node.
    unsigned* rsorted = (unsigned*)alloc((size_t)MAXE * 4);        // 4.8 MB
    unsigned* flagbuf = (unsigned*)alloc(256 * 4);    // [32..227]=dp flags
    unsigned* ghist   = (unsigned*)alloc((size_t)NR * NB * 4);     // [rel][NB]
    unsigned* rngs    = (unsigned*)alloc((size_t)NR * 2 * 4);
    int*      chunkrel= (int*)     alloc((size_t)NCHUNK * 4);
    unsigned short* rank16 = (unsigned short*)alloc((size_t)MAXE * 2);
    unsigned short* cnt16  = (unsigned short*)alloc((size_t)NR * NN * 2); // 4.5 MB
    unsigned* packed  = (unsigned*)alloc((size_t)NR * NN * 4);     // 9.0 MB
    unsigned* rowptr  = (unsigned*)alloc(((size_t)NN + 1) * 4);
    uint2*    pedges  = (uint2*)   alloc((size_t)MAXE * 8);        // 9.6 MB
    __half*   W1f     = (__half*)  alloc((size_t)NR * 2048 * 2);
    __half*   W2f     = (__half*)  alloc((size_t)NR * 512 * 2);
    __half*   xh      = (__half*)  alloc((size_t)NN * INC * 2);    // 6.4 MB
    __half*   hh      = (__half*)  alloc((size_t)NN * HIDC * 2);   // 3.2 MB
    float2*   rootp1  = (float2*)  alloc(1024 * 8);                // 8 KB
    float2*   rootp2  = (float2*)  alloc(256 * 8);                 // 2 KB
    float2*   b1p     = (float2*)  alloc(16 * 8);
    // msg buffers alias: msg1 (f16, 64-B rows) fully consumed by gather1
    // before msg2 (f16, 32-B rows) is produced.
    char*     msgraw  = alloc(((size_t)NE + 1) * 64);              // 76.9 MB
    __half*   msg1    = (__half*)msgraw;
    __half*   msg2    = (__half*)msgraw;

    int prep_grid = NN * INC / 2 / 256;   // 6250 >= NB, covers all prep work
    preph_k   <<<prep_grid, 256, 0, stream>>>(W1, W2, x, ei, et, root1, root2, b1,
                                              W1f, W2f, xh, rootp1, rootp2, b1p,
                                              ghist, rsorted, flagbuf);
    scat_k    <<<NB, 1024, 0, stream>>>(ei, et, ghist, rngs, chunkrel, rsorted);
    relcnt_k  <<<4 * NR, 1024, 0, stream>>>(rsorted, rngs, cnt16, rank16);
    dp_k      <<<NTILE, 256, 0, stream>>>(cnt16, packed, rowptr, flagbuf + 32);
    msg1_k    <<<(MAXE + 255) / 256, 256, 0, stream>>>(xh, W1f, rsorted, rank16,
                                                       packed, rowptr, chunkrel,
                                                       pedges, msg1);
    gather1_k <<<NN * 64 / 256, 256, 0, stream>>>(xh, rootp1, b1p, msg1, rowptr, hh);
    msg2_k    <<<(MAXE + 255) / 256, 256, 0, stream>>>(hh, W2f, pedges, msg2);
    gather2_k <<<NN * 64 / 256, 256, 0, stream>>>(hh, rootp2, b2, msg2, rowptr, out);
}